// Round 1
// baseline (11870.979 us; speedup 1.0000x reference)
//
#include <hip/hip_runtime.h>

typedef unsigned long long ull;

#define EMB 512
#define HID 1024
#define NV  32000
#define NB  4
#define NT  64

__device__ __forceinline__ ull umax64(ull a, ull b) { return a > b ? a : b; }
__device__ __forceinline__ ull umin64(ull a, ull b) { return a < b ? a : b; }

// Total-order key: larger value first, ties -> lower index (matches jax.lax.top_k)
__device__ __forceinline__ ull packkey(float v, unsigned idx) {
  unsigned u = __float_as_uint(v);
  u ^= (u >> 31) ? 0xFFFFFFFFu : 0x80000000u;
  return ((ull)u << 32) | (ull)(0xFFFFFFFFu - idx);
}

// ---------------------------------------------------------------------------
// Two-level grid barrier (8 arrival lanes -> 1 mid counter -> gen release).
// Data visibility across non-coherent XCD L2s: __threadfence() (agent-scope
// wb/inv) before arrive and after release observed; atomics agent-scope.
// ---------------------------------------------------------------------------
struct GridBar { unsigned cnt[8 * 32]; unsigned mid[32]; unsigned gen[32]; };

__device__ __forceinline__ void gridbar(GridBar* gb, int W) {
  __syncthreads();                 // drains all waves' vmem (compiler emits vmcnt(0))
  if (threadIdx.x == 0) {
    __threadfence();               // release: L2 writeback to coherent point
    const int lane = (int)(blockIdx.x & 7);
    const int rem = W & 7;
    const unsigned nlane = (unsigned)((W >> 3) + (lane < rem ? 1 : 0));
    const unsigned nlanes = (unsigned)(W < 8 ? W : 8);
    unsigned g = __hip_atomic_load(&gb->gen[0], __ATOMIC_RELAXED, __HIP_MEMORY_SCOPE_AGENT);
    unsigned a = __hip_atomic_fetch_add(&gb->cnt[lane * 32], 1u, __ATOMIC_RELAXED,
                                        __HIP_MEMORY_SCOPE_AGENT);
    if (a == nlane - 1u) {
      __hip_atomic_store(&gb->cnt[lane * 32], 0u, __ATOMIC_RELAXED, __HIP_MEMORY_SCOPE_AGENT);
      unsigned m = __hip_atomic_fetch_add(&gb->mid[0], 1u, __ATOMIC_RELAXED,
                                          __HIP_MEMORY_SCOPE_AGENT);
      if (m == nlanes - 1u) {
        __hip_atomic_store(&gb->mid[0], 0u, __ATOMIC_RELAXED, __HIP_MEMORY_SCOPE_AGENT);
        __hip_atomic_store(&gb->gen[0], g + 1u, __ATOMIC_RELEASE, __HIP_MEMORY_SCOPE_AGENT);
      }
    }
    while (__hip_atomic_load(&gb->gen[0], __ATOMIC_RELAXED, __HIP_MEMORY_SCOPE_AGENT) == g)
      __builtin_amdgcn_s_sleep(2);
    __threadfence();               // acquire: invalidate stale L1/L2 lines
  }
  __syncthreads();
}

__global__ void k_zero(unsigned* w) {
  if (threadIdx.x < sizeof(GridBar) / 4) w[threadIdx.x] = 0;
}

// ---------------------------------------------------------------------------
// GEMM panel core (LDS passed in so it can live in a per-kernel union).
// Numerics identical to the proven version: per-thread FMA order is strictly
// ascending k regardless of SECK sectioning.
// ---------------------------------------------------------------------------
template<int SECK>
__device__ __forceinline__ void gemm_panel_m(
    float* __restrict__ xlds,                  // [SECK*32]
    float (* __restrict__ wlds)[2][1024],      // [4 waves][2 buf][16*64]
    const float* __restrict__ Wrow, int K, int kb0, int nsec,
    const float* __restrict__ xT, float* __restrict__ outP)
{
  const int t = threadIdx.x;
  const int l = t & 63;
  const int wq = t >> 6;
  const int jg = l & 7;
  const int ng = l >> 3;
  const int lrow = l >> 2;
  const int lk4 = (l & 3) * 4;

  float acc[8][4];
#pragma unroll
  for (int i = 0; i < 8; ++i)
#pragma unroll
    for (int q = 0; q < 4; ++q) acc[i][q] = 0.f;

  for (int sec = 0; sec < nsec; ++sec) {
    const int ks = kb0 + sec * SECK;
    __syncthreads();
    {
      const float* src = xT + (size_t)ks * 32;
      for (int i = t * 4; i < SECK * 32; i += 1024)
        *(float4*)(&xlds[i]) = *(const float4*)(src + i);
    }
    __syncthreads();

    const float* wsrc = Wrow + (size_t)(wq * 64 + lrow) * K + ks + lk4;
    const int nch = SECK / 16;

    float4 wr[4];
#pragma unroll
    for (int p = 0; p < 4; ++p) wr[p] = *(const float4*)(wsrc + (size_t)(p * 16) * K);
#pragma unroll
    for (int p = 0; p < 4; ++p) {
      float* wd = &wlds[wq][0][0];
      wd[(lk4 + 0) * 64 + p * 16 + lrow] = wr[p].x;
      wd[(lk4 + 1) * 64 + p * 16 + lrow] = wr[p].y;
      wd[(lk4 + 2) * 64 + p * 16 + lrow] = wr[p].z;
      wd[(lk4 + 3) * 64 + p * 16 + lrow] = wr[p].w;
    }
    int buf = 0;
    for (int c = 0; c < nch; ++c) {
      if (c + 1 < nch) {
#pragma unroll
        for (int p = 0; p < 4; ++p)
          wr[p] = *(const float4*)(wsrc + (size_t)(p * 16) * K + (c + 1) * 16);
      }
      const float* wb = &wlds[wq][buf][0];
      const float* xb = xlds + (size_t)(c * 16) * 32;
#pragma unroll
      for (int k = 0; k < 16; ++k) {
        float4 w0 = *(const float4*)(wb + k * 64 + jg * 8);
        float4 w1 = *(const float4*)(wb + k * 64 + jg * 8 + 4);
        float4 xv = *(const float4*)(xb + k * 32 + ng * 4);
        acc[0][0] = fmaf(w0.x, xv.x, acc[0][0]); acc[0][1] = fmaf(w0.x, xv.y, acc[0][1]);
        acc[0][2] = fmaf(w0.x, xv.z, acc[0][2]); acc[0][3] = fmaf(w0.x, xv.w, acc[0][3]);
        acc[1][0] = fmaf(w0.y, xv.x, acc[1][0]); acc[1][1] = fmaf(w0.y, xv.y, acc[1][1]);
        acc[1][2] = fmaf(w0.y, xv.z, acc[1][2]); acc[1][3] = fmaf(w0.y, xv.w, acc[1][3]);
        acc[2][0] = fmaf(w0.z, xv.x, acc[2][0]); acc[2][1] = fmaf(w0.z, xv.y, acc[2][1]);
        acc[2][2] = fmaf(w0.z, xv.z, acc[2][2]); acc[2][3] = fmaf(w0.z, xv.w, acc[2][3]);
        acc[3][0] = fmaf(w0.w, xv.x, acc[3][0]); acc[3][1] = fmaf(w0.w, xv.y, acc[3][1]);
        acc[3][2] = fmaf(w0.w, xv.z, acc[3][2]); acc[3][3] = fmaf(w0.w, xv.w, acc[3][3]);
        acc[4][0] = fmaf(w1.x, xv.x, acc[4][0]); acc[4][1] = fmaf(w1.x, xv.y, acc[4][1]);
        acc[4][2] = fmaf(w1.x, xv.z, acc[4][2]); acc[4][3] = fmaf(w1.x, xv.w, acc[4][3]);
        acc[5][0] = fmaf(w1.y, xv.x, acc[5][0]); acc[5][1] = fmaf(w1.y, xv.y, acc[5][1]);
        acc[5][2] = fmaf(w1.y, xv.z, acc[5][2]); acc[5][3] = fmaf(w1.y, xv.w, acc[5][3]);
        acc[6][0] = fmaf(w1.z, xv.x, acc[6][0]); acc[6][1] = fmaf(w1.z, xv.y, acc[6][1]);
        acc[6][2] = fmaf(w1.z, xv.z, acc[6][2]); acc[6][3] = fmaf(w1.z, xv.w, acc[6][3]);
        acc[7][0] = fmaf(w1.w, xv.x, acc[7][0]); acc[7][1] = fmaf(w1.w, xv.y, acc[7][1]);
        acc[7][2] = fmaf(w1.w, xv.z, acc[7][2]); acc[7][3] = fmaf(w1.w, xv.w, acc[7][3]);
      }
      if (c + 1 < nch) {
        float* wd = &wlds[wq][buf ^ 1][0];
#pragma unroll
        for (int p = 0; p < 4; ++p) {
          wd[(lk4 + 0) * 64 + p * 16 + lrow] = wr[p].x;
          wd[(lk4 + 1) * 64 + p * 16 + lrow] = wr[p].y;
          wd[(lk4 + 2) * 64 + p * 16 + lrow] = wr[p].z;
          wd[(lk4 + 3) * 64 + p * 16 + lrow] = wr[p].w;
        }
      }
      buf ^= 1;
    }
  }

#pragma unroll
  for (int i = 0; i < 8; ++i)
    *(float4*)(outP + (size_t)(wq * 64 + jg * 8 + i) * 32 + ng * 4) =
        make_float4(acc[i][0], acc[i][1], acc[i][2], acc[i][3]);
}

// ---------------------------------------------------------------------------
// Phase bodies (shared between the mega-kernel and the fallback kernels).
// ---------------------------------------------------------------------------
__device__ __forceinline__ void combine_one(
    int g, const float* __restrict__ gHp, const float* __restrict__ gIp,
    const float* __restrict__ bih, const float* __restrict__ bhh,
    const float* __restrict__ hT, float* __restrict__ h2T)
{
  int n = g & 31, i = g >> 5;
  float gir = bih[i], giz = bih[1024 + i], gin = bih[2048 + i];
#pragma unroll
  for (int s = 0; s < 4; ++s) {
    const float* P = gIp + (size_t)s * (3072 * 32);
    gir += P[(size_t)i * 32 + n];
    giz += P[(size_t)(1024 + i) * 32 + n];
    gin += P[(size_t)(2048 + i) * 32 + n];
  }
  float ghr = bhh[i], ghz = bhh[1024 + i], ghn = bhh[2048 + i];
#pragma unroll
  for (int s = 0; s < 8; ++s) {
    const float* P = gHp + (size_t)s * (3072 * 32);
    ghr += P[(size_t)i * 32 + n];
    ghz += P[(size_t)(1024 + i) * 32 + n];
    ghn += P[(size_t)(2048 + i) * 32 + n];
  }
  float r = 1.f / (1.f + expf(-(gir + ghr)));
  float z = 1.f / (1.f + expf(-(giz + ghz)));
  float nn = tanhf(gin + r * ghn);
  h2T[g] = (1.f - z) * nn + z * hT[g];
}

__device__ __forceinline__ void reduce_one(
    int bx, float (* __restrict__ tile)[33],
    const float* __restrict__ logitsP, const float* __restrict__ bout,
    float* __restrict__ logitsN, float* __restrict__ lsePart, int NS)
{
  const int t = threadIdx.x;
  const int j0 = bx * 64;

  {
    const int n = t & 31;
    const int jb = (t >> 5) * 8;
    float v[8];
#pragma unroll
    for (int i = 0; i < 8; ++i) v[i] = bout[j0 + jb + i];
    for (int s = 0; s < NS; ++s) {
      const float* P = logitsP + (size_t)s * (NV * 32) + (size_t)(j0 + jb) * 32 + n;
#pragma unroll
      for (int i = 0; i < 8; ++i) v[i] += P[(size_t)i * 32];
    }
#pragma unroll
    for (int i = 0; i < 8; ++i) tile[jb + i][n] = v[i];
  }
  __syncthreads();
  {
    const int jl = t & 63;
    const int wq = t >> 6;
#pragma unroll
    for (int q = 0; q < 8; ++q) {
      const int nn = wq * 8 + q;
      float val = tile[jl][nn];
      logitsN[(size_t)nn * NV + j0 + jl] = val;
      float m = val;
      m = fmaxf(m, __shfl_xor(m, 1, 64));
      m = fmaxf(m, __shfl_xor(m, 2, 64));
      m = fmaxf(m, __shfl_xor(m, 4, 64));
      m = fmaxf(m, __shfl_xor(m, 8, 64));
      m = fmaxf(m, __shfl_xor(m, 16, 64));
      m = fmaxf(m, __shfl_xor(m, 32, 64));
      float sx = expf(val - m);
      sx += __shfl_xor(sx, 1, 64);
      sx += __shfl_xor(sx, 2, 64);
      sx += __shfl_xor(sx, 4, 64);
      sx += __shfl_xor(sx, 8, 64);
      sx += __shfl_xor(sx, 16, 64);
      sx += __shfl_xor(sx, 32, 64);
      if (jl == 0) {
        lsePart[(size_t)bx * 64 + nn * 2] = m;
        lsePart[(size_t)bx * 64 + nn * 2 + 1] = sx;
      }
    }
  }
}

struct TAsh { float pm[32][8]; float ps[32][8]; float A[8]; ull wm[4]; };

__device__ __forceinline__ void topkA_one(
    int b, int c, TAsh* S,
    const float* __restrict__ logitsN, const float* __restrict__ lsePart,
    const float* __restrict__ prev_vals, const int* __restrict__ prev_tok,
    int eos, ull* __restrict__ top8A, int mode)
{
  const int t = threadIdx.x;

  // phase 1: finish logsumexp over 500 partials
  {
    const int n8 = t & 7;
    const int grp = t >> 3;
    float m = -3.0e38f, s = 0.f;
    for (int p = grp; p < 500; p += 32) {
      float2 q = *(const float2*)(lsePart + (size_t)p * 64 + (b * 8 + n8) * 2);
      float Mx = fmaxf(m, q.x);
      s = s * expf(m - Mx) + q.y * expf(q.x - Mx);
      m = Mx;
    }
    S->pm[grp][n8] = m; S->ps[grp][n8] = s;
    __syncthreads();
    for (int off2 = 16; off2 >= 1; off2 >>= 1) {
      if (grp < off2) {
        float m1 = S->pm[grp][n8], s1 = S->ps[grp][n8];
        float m2 = S->pm[grp + off2][n8], s2 = S->ps[grp + off2][n8];
        float Mx = fmaxf(m1, m2);
        S->pm[grp][n8] = Mx;
        S->ps[grp][n8] = s1 * expf(m1 - Mx) + s2 * expf(m2 - Mx);
      }
      __syncthreads();
    }
    if (t < 8) S->A[t] = S->pm[0][t] + logf(S->ps[0][t]);
    __syncthreads();
  }

  ull t8[8];
#pragma unroll
  for (int j = 0; j < 8; ++j) t8[j] = 0ULL;

  if (mode == 1) {
    const int kb = c >> 2;
    const int v0 = (c & 3) * 8000;
    const bool fin = (prev_tok[b * 8 + kb] == eos);
    const float add = prev_vals[b * 8 + kb] - S->A[kb];
    const float* row = logitsN + (size_t)(b * 8 + kb) * NV;
    for (int v = v0 + t; v < v0 + 8000; v += 256) {
      float val;
      if (fin) val = (v == eos) ? 0.f : -1e30f;
      else val = row[v] + add;
      ull key = packkey(val, (unsigned)(kb * NV + v));
      if (key > t8[7]) {
        t8[7] = key;
#pragma unroll
        for (int q = 7; q >= 1; --q) {
          ull hi = umax64(t8[q - 1], t8[q]);
          ull lo = umin64(t8[q - 1], t8[q]);
          t8[q - 1] = hi; t8[q] = lo;
        }
      }
    }
  } else {
    const int v0 = c * 1000;
    const float add = -S->A[0];
    const float* row = logitsN + (size_t)(b * 8) * NV;
    for (int v = v0 + t; v < v0 + 1000; v += 256) {
      float val = row[v] + add;
      ull key = packkey(val, (unsigned)v);
      if (key > t8[7]) {
        t8[7] = key;
#pragma unroll
        for (int q = 7; q >= 1; --q) {
          ull hi = umax64(t8[q - 1], t8[q]);
          ull lo = umin64(t8[q - 1], t8[q]);
          t8[q - 1] = hi; t8[q] = lo;
        }
      }
    }
  }

  // 8-round exact extraction (keys unique)
  int pi = 0;
  for (int r = 0; r < 8; ++r) {
    ull cand = (pi < 8) ? t8[pi] : 0ULL;
#pragma unroll
    for (int off = 1; off < 64; off <<= 1) cand = umax64(cand, __shfl_xor(cand, off, 64));
    if ((t & 63) == 0) S->wm[t >> 6] = cand;
    __syncthreads();
    ull win = umax64(umax64(S->wm[0], S->wm[1]), umax64(S->wm[2], S->wm[3]));
    if (pi < 8 && t8[pi] == win) ++pi;
    if (t == 0) top8A[((size_t)b * 32 + c) * 8 + r] = win;
    __syncthreads();
  }
}

struct TBsh { ull wm[4]; float vals8[8]; int tok8[8]; int which8[8]; };

__device__ __forceinline__ void topkB_one(
    int b, TBsh* S, const ull* __restrict__ top8A,
    float* __restrict__ prev_vals, int* __restrict__ prev_tok,
    const float* __restrict__ lp_src, float* __restrict__ lp_dst,
    const int* __restrict__ tok_src, int* __restrict__ tok_dst,
    const float* __restrict__ h2T, float* __restrict__ hT,
    const float* __restrict__ emb, float* __restrict__ embX,
    int step, int mode)
{
  const int t = threadIdx.x;

  ull mykey = top8A[(size_t)b * 256 + t];
  int done = 0;
  for (int r = 0; r < 8; ++r) {
    ull cand = done ? 0ULL : mykey;
#pragma unroll
    for (int off = 1; off < 64; off <<= 1) cand = umax64(cand, __shfl_xor(cand, off, 64));
    if ((t & 63) == 0) S->wm[t >> 6] = cand;
    __syncthreads();
    ull win = umax64(umax64(S->wm[0], S->wm[1]), umax64(S->wm[2], S->wm[3]));
    if (!done && mykey == win) done = 1;
    if (t == 0) {
      unsigned idx = 0xFFFFFFFFu - (unsigned)(win & 0xFFFFFFFFull);
      unsigned u = (unsigned)(win >> 32);
      u = (u >> 31) ? (u ^ 0x80000000u) : ~u;
      S->vals8[r] = __uint_as_float(u);
      if (mode == 1) { S->tok8[r] = (int)(idx % NV); S->which8[r] = (int)(idx / NV); }
      else { S->tok8[r] = (int)idx; S->which8[r] = r; }
    }
    __syncthreads();
  }

  if (t < 8) {
    prev_vals[b * 8 + t] = S->vals8[t];
    prev_tok[b * 8 + t] = S->tok8[t];
  }
  for (int idx = t; idx < 512; idx += 256) {
    int j = idx >> 6;
    int tt = idx & 63;
    float lv; int tv;
    if (tt == step) { lv = S->vals8[j]; tv = S->tok8[j]; }
    else if (mode == 0) { lv = 0.f; tv = 0; }
    else {
      int w = S->which8[j];
      lv = lp_src[b * 512 + w * 64 + tt];
      tv = tok_src[b * 512 + w * 64 + tt];
    }
    lp_dst[b * 512 + idx] = lv;
    tok_dst[b * 512 + idx] = tv;
  }
  for (int idx = t; idx < 8192; idx += 256) {
    int kk = idx >> 3;
    int j = idx & 7;
    hT[kk * 32 + b * 8 + j] = h2T[kk * 32 + b * 8 + S->which8[j]];
  }
  {
    int j = t >> 5;
    int kbase = (t & 31) * 16;
    const float* src = emb + (size_t)S->tok8[j] * EMB + kbase;
#pragma unroll
    for (int q = 0; q < 4; ++q) {
      float4 v = *(const float4*)(src + 4 * q);
      embX[(kbase + 4 * q + 0) * 32 + b * 8 + j] = v.x;
      embX[(kbase + 4 * q + 1) * 32 + b * 8 + j] = v.y;
      embX[(kbase + 4 * q + 2) * 32 + b * 8 + j] = v.z;
      embX[(kbase + 4 * q + 3) * 32 + b * 8 + j] = v.w;
    }
  }
}

// ---------------------------------------------------------------------------
// Mega-kernel: entire 64-step beam-search loop in one cooperative launch.
// 48 KiB LDS union -> >=2 WGs/CU; all phases grid-stride so any W works.
// ---------------------------------------------------------------------------
union MegaLDS {
  struct { float x[128 * 32]; float w[4][2][1024]; } gp;  // 48 KiB
  float tile[64][33];
  TAsh ta;
  TBsh tb;
};

struct MegaArgs {
  const float* encoded; const float* embedding;
  const float* Wih; const float* Whh; const float* bih; const float* bhh;
  const float* Wout; const float* bout;
  const int* bosp; const int* eosp;
  float* hT; float* h2T; float* embX; float* gHp; float* gIp;
  float* logitsN; float* lsePart; ull* top8A;
  float* prev_vals; int* prev_tok;
  float* lp0; float* lp1; int* tok0; int* tok1;
  float* logitsP; int NS;
  GridBar* gb; float* outp;
};

__global__ __launch_bounds__(256, 2) void k_mega(MegaArgs a)
{
  __shared__ MegaLDS L;
  const int W = (int)gridDim.x;
  const int bid = (int)blockIdx.x;
  const int t = (int)threadIdx.x;
  const int KperS = 1024 / a.NS;
  const int NPANL = 125 * a.NS;

  // prep: hT / embX for step 0
  for (int g = bid * 256 + t; g < 49152; g += W * 256) {
    if (g < 32768) {
      int k = g >> 5, n = g & 31;
      a.hT[g] = a.encoded[(n >> 3) * HID + k];
    } else {
      int g2 = g - 32768;
      int k = g2 >> 5;
      a.embX[g2] = a.embedding[(size_t)(*a.bosp) * EMB + k];
    }
  }
  gridbar(a.gb, W);
  const int eos = *a.eosp;

  for (int st = 0; st < NT; ++st) {
    // ---- gates (144 panels, identical K-split to the proven kernel) ----
    for (int p = bid; p < 144; p += W) {
      if (p < 96) {
        int jt = p % 12, s = p / 12;
        gemm_panel_m<128>(L.gp.x, L.gp.w, a.Whh + (size_t)jt * 256 * HID, HID, s * 128, 1,
                          a.hT, a.gHp + (size_t)s * (3072 * 32) + (size_t)jt * 256 * 32);
      } else {
        int r = p - 96, jt = r % 12, s = r / 12;
        gemm_panel_m<128>(L.gp.x, L.gp.w, a.Wih + (size_t)jt * 256 * EMB, EMB, s * 128, 1,
                          a.embX, a.gIp + (size_t)s * (3072 * 32) + (size_t)jt * 256 * 32);
      }
    }
    gridbar(a.gb, W);

    // ---- combine -> h2T ----
    for (int g = bid * 256 + t; g < 32768; g += W * 256)
      combine_one(g, a.gHp, a.gIp, a.bih, a.bhh, a.hT, a.h2T);
    gridbar(a.gb, W);

    // ---- logits (125*NS panels) ----
    for (int p = bid; p < NPANL; p += W) {
      int jt = p % 125, s = p / 125;
      gemm_panel_m<128>(L.gp.x, L.gp.w, a.Wout + (size_t)jt * 256 * HID, HID, s * KperS,
                        KperS / 128, a.h2T,
                        a.logitsP + (size_t)s * (NV * 32) + (size_t)jt * 256 * 32);
    }
    gridbar(a.gb, W);

    // ---- reduce: sum slabs + bias, transpose, lse partials ----
    for (int c = bid; c < 500; c += W) {
      reduce_one(c, L.tile, a.logitsP, a.bout, a.logitsN, a.lsePart, a.NS);
      __syncthreads();
    }
    gridbar(a.gb, W);

    const int mode = (st == 0) ? 0 : 1;

    // ---- topkA (128 items) ----
    for (int it = bid; it < 128; it += W)
      topkA_one(it >> 5, it & 31, &L.ta, a.logitsN, a.lsePart, a.prev_vals, a.prev_tok,
                eos, a.top8A, mode);
    gridbar(a.gb, W);

    // ---- topkB (4 items) ----
    {
      float* lps = (st & 1) ? a.lp0 : a.lp1;
      float* lpd = (st & 1) ? a.lp1 : a.lp0;
      int* tks = (st & 1) ? a.tok0 : a.tok1;
      int* tkd = (st & 1) ? a.tok1 : a.tok0;
      for (int b = bid; b < NB; b += W)
        topkB_one(b, &L.tb, a.top8A, a.prev_vals, a.prev_tok, lps, lpd, tks, tkd,
                  a.h2T, a.hT, a.embedding, a.embX, st, mode);
    }
    gridbar(a.gb, W);
  }

  // final: out = [lp_hist, tok_hist as float]
  for (int g = bid * 256 + t; g < 4096; g += W * 256) {
    if (g < 2048) a.outp[g] = a.lp1[g];
    else a.outp[g] = (float)a.tok1[g - 2048];
  }
}

// ---------------------------------------------------------------------------
// Fallback kernels (original multi-launch path), sharing the same bodies.
// ---------------------------------------------------------------------------
__global__ void k_prep(const float* __restrict__ encoded, const float* __restrict__ emb,
                       const int* __restrict__ bosp,
                       float* __restrict__ hT, float* __restrict__ embX)
{
  int g = blockIdx.x * 256 + threadIdx.x;   // 49152
  if (g < 32768) {
    int k = g >> 5, n = g & 31;
    hT[g] = encoded[(n >> 3) * HID + k];
  } else {
    int g2 = g - 32768;
    int k = g2 >> 5;
    embX[g2] = emb[(size_t)(*bosp) * EMB + k];
  }
}

__global__ __launch_bounds__(256, 2) void k_gates(
    const float* __restrict__ Wih, const float* __restrict__ Whh,
    const float* __restrict__ embX, const float* __restrict__ hT,
    float* __restrict__ gHp, float* __restrict__ gIp)
{
  __shared__ float xlds[128 * 32];
  __shared__ float wlds[4][2][1024];
  const int bx = blockIdx.x;
  if (bx < 96) {
    const int jt = bx % 12, s = bx / 12;
    gemm_panel_m<128>(xlds, wlds, Whh + (size_t)jt * 256 * HID, HID, s * 128, 1, hT,
                      gHp + (size_t)s * (3072 * 32) + (size_t)jt * 256 * 32);
  } else {
    const int r = bx - 96;
    const int jt = r % 12, s = r / 12;
    gemm_panel_m<128>(xlds, wlds, Wih + (size_t)jt * 256 * EMB, EMB, s * 128, 1, embX,
                      gIp + (size_t)s * (3072 * 32) + (size_t)jt * 256 * 32);
  }
}

__global__ __launch_bounds__(256) void k_combine(
    const float* __restrict__ gHp, const float* __restrict__ gIp,
    const float* __restrict__ bih, const float* __restrict__ bhh,
    const float* __restrict__ hT, float* __restrict__ h2T)
{
  int g = blockIdx.x * 256 + threadIdx.x;   // 32768
  combine_one(g, gHp, gIp, bih, bhh, hT, h2T);
}

__global__ __launch_bounds__(256, 2) void k_logits(
    const float* __restrict__ Wout, const float* __restrict__ h2T,
    float* __restrict__ logitsP, int NS)
{
  __shared__ float xlds[128 * 32];
  __shared__ float wlds[4][2][1024];
  const int jt = blockIdx.x % 125;
  const int s = blockIdx.x / 125;
  const int KperS = 1024 / NS;
  gemm_panel_m<128>(xlds, wlds, Wout + (size_t)jt * 256 * HID, HID, s * KperS, KperS / 128,
                    h2T, logitsP + (size_t)s * (NV * 32) + (size_t)jt * 256 * 32);
}

__global__ __launch_bounds__(256) void k_reduce(
    const float* __restrict__ logitsP, const float* __restrict__ bout,
    float* __restrict__ logitsN, float* __restrict__ lsePart, int NS)
{
  __shared__ float tile[64][33];
  reduce_one(blockIdx.x, tile, logitsP, bout, logitsN, lsePart, NS);
}

__global__ __launch_bounds__(256) void k_topkA(
    const float* __restrict__ logitsN, const float* __restrict__ lsePart,
    const float* __restrict__ prev_vals, const int* __restrict__ prev_tok,
    const int* __restrict__ eosp, ull* __restrict__ top8A, int mode)
{
  __shared__ TAsh S;
  topkA_one(blockIdx.x >> 5, blockIdx.x & 31, &S, logitsN, lsePart, prev_vals, prev_tok,
            *eosp, top8A, mode);
}

__global__ __launch_bounds__(256) void k_topkB(
    const ull* __restrict__ top8A,
    float* __restrict__ prev_vals, int* __restrict__ prev_tok,
    const float* __restrict__ lp_src, float* __restrict__ lp_dst,
    const int* __restrict__ tok_src, int* __restrict__ tok_dst,
    const float* __restrict__ h2T, float* __restrict__ hT,
    const float* __restrict__ emb, float* __restrict__ embX,
    int step, int mode)
{
  __shared__ TBsh S;
  topkB_one(blockIdx.x, &S, top8A, prev_vals, prev_tok, lp_src, lp_dst, tok_src, tok_dst,
            h2T, hT, emb, embX, step, mode);
}

__global__ void k_final(const float* __restrict__ lp_hist, const int* __restrict__ tok_hist,
                        float* __restrict__ out)
{
  int g = blockIdx.x * 256 + threadIdx.x;   // 4096
  if (g < 2048) out[g] = lp_hist[g];
  else out[g] = (float)tok_hist[g - 2048];
}

extern "C" void kernel_launch(void* const* d_in, const int* in_sizes, int n_in,
                              void* d_out, int out_size, void* d_ws, size_t ws_size,
                              hipStream_t stream)
{
  (void)in_sizes; (void)n_in; (void)out_size;
  const float* encoded   = (const float*)d_in[0];
  const float* embedding = (const float*)d_in[1];
  const float* Wih       = (const float*)d_in[2];
  const float* Whh       = (const float*)d_in[3];
  const float* bih       = (const float*)d_in[4];
  const float* bhh       = (const float*)d_in[5];
  const float* Wout      = (const float*)d_in[6];
  const float* bout      = (const float*)d_in[7];
  const int*   bosp      = (const int*)d_in[8];
  const int*   eosp      = (const int*)d_in[9];

  char* p = (char*)d_ws;
  size_t off = 0;
  auto ALLOC = [&](size_t bytes) -> void* {
    void* r = p + off;
    off += (bytes + 255) & ~(size_t)255;
    return r;
  };
  float* hT        = (float*)ALLOC((size_t)HID * 32 * 4);
  float* h2T       = (float*)ALLOC((size_t)HID * 32 * 4);
  float* embX      = (float*)ALLOC((size_t)EMB * 32 * 4);
  float* gHp       = (float*)ALLOC((size_t)8 * 3072 * 32 * 4);   // 3.15 MB
  float* gIp       = (float*)ALLOC((size_t)4 * 3072 * 32 * 4);   // 1.57 MB
  // logitsN overlays gHp+gIp (consumed by combine before reduce writes it;
  // gates rewrites next step only after topkA has consumed logitsN).
  float* logitsN   = gHp;
  float* lsePart   = (float*)ALLOC((size_t)500 * 64 * 4);
  ull*   top8A     = (ull*)ALLOC((size_t)NB * 32 * 8 * 8);
  float* prev_vals = (float*)ALLOC(32 * 4);
  int*   prev_tok  = (int*)ALLOC(32 * 4);
  float* lp0       = (float*)ALLOC(2048 * 4);
  float* lp1       = (float*)ALLOC(2048 * 4);
  int*   tok0      = (int*)ALLOC(2048 * 4);
  int*   tok1      = (int*)ALLOC(2048 * 4);
  GridBar* gb      = (GridBar*)ALLOC(sizeof(GridBar));

  int NS = 4;
  if (off + (size_t)4 * NV * 32 * 4 > ws_size) NS = 2;
  if (off + (size_t)2 * NV * 32 * 4 > ws_size) NS = 1;
  float* logitsP = (float*)ALLOC((size_t)NS * NV * 32 * 4);

  // ---- preferred path: one cooperative launch for the whole loop ----
  k_zero<<<1, 512, 0, stream>>>((unsigned*)gb);

  MegaArgs ma;
  ma.encoded = encoded; ma.embedding = embedding;
  ma.Wih = Wih; ma.Whh = Whh; ma.bih = bih; ma.bhh = bhh;
  ma.Wout = Wout; ma.bout = bout; ma.bosp = bosp; ma.eosp = eosp;
  ma.hT = hT; ma.h2T = h2T; ma.embX = embX; ma.gHp = gHp; ma.gIp = gIp;
  ma.logitsN = logitsN; ma.lsePart = lsePart; ma.top8A = top8A;
  ma.prev_vals = prev_vals; ma.prev_tok = prev_tok;
  ma.lp0 = lp0; ma.lp1 = lp1; ma.tok0 = tok0; ma.tok1 = tok1;
  ma.logitsP = logitsP; ma.NS = NS; ma.gb = gb; ma.outp = (float*)d_out;

  int occ = 0;
  if (hipOccupancyMaxActiveBlocksPerMultiprocessor(&occ, k_mega, 256, 0) != hipSuccess ||
      occ < 1) occ = 1;
  int W = (occ >= 2) ? 500 : 250;

  void* kargs[] = { &ma };
  hipError_t e = hipLaunchCooperativeKernel(k_mega, dim3(W), dim3(256), kargs, 0, stream);
  if (e == hipSuccess) return;
  (void)hipGetLastError();  // clear error state; fall back to multi-launch path

  // ---- fallback: original (proven) multi-launch sequence ----
  k_prep<<<192, 256, 0, stream>>>(encoded, embedding, bosp, hT, embX);
  for (int t = 0; t < NT; ++t) {
    k_gates<<<144, 256, 0, stream>>>(Wih, Whh, embX, hT, gHp, gIp);
    k_combine<<<128, 256, 0, stream>>>(gHp, gIp, bih, bhh, hT, h2T);
    k_logits<<<125 * NS, 256, 0, stream>>>(Wout, h2T, logitsP, NS);
    k_reduce<<<500, 256, 0, stream>>>(logitsP, bout, logitsN, lsePart, NS);
    const int mode = (t == 0) ? 0 : 1;
    k_topkA<<<128, 256, 0, stream>>>(logitsN, lsePart, prev_vals, prev_tok, eosp, top8A, mode);
    float* lps = (t & 1) ? lp0 : lp1;
    float* lpd = (t & 1) ? lp1 : lp0;
    int*   tks = (t & 1) ? tok0 : tok1;
    int*   tkd = (t & 1) ? tok1 : tok0;
    k_topkB<<<NB, 256, 0, stream>>>(top8A, prev_vals, prev_tok, lps, lpd, tks, tkd,
                                    h2T, hT, embedding, embX, t, mode);
  }
  k_final<<<16, 256, 0, stream>>>(lp1, tok1, (float*)d_out);
}

// Round 3
// 9599.875 us; speedup vs baseline: 1.2366x; 1.2366x over previous
//
#include <hip/hip_runtime.h>

typedef unsigned long long ull;

#define EMB 512
#define HID 1024
#define NV  32000
#define NB  4
#define NT  64
#define WP  68   // wlds pitch in floats: 16B-aligned reads, 2-way (free) bank conflicts

__device__ __forceinline__ ull umax64(ull a, ull b) { return a > b ? a : b; }
__device__ __forceinline__ ull umin64(ull a, ull b) { return a < b ? a : b; }

// Total-order key: larger value first, ties -> lower index (matches jax.lax.top_k)
__device__ __forceinline__ ull packkey(float v, unsigned idx) {
  unsigned u = __float_as_uint(v);
  u ^= (u >> 31) ? 0xFFFFFFFFu : 0x80000000u;
  return ((ull)u << 32) | (ull)(0xFFFFFFFFu - idx);
}

// ---------------------------------------------------------------------------
// Coherent (agent-scope, relaxed) accessors for cross-phase intermediates.
// Compile to single global_load/store with sc bits -> read/write the coherent
// point. NO cache-flush fences needed anywhere.
// ---------------------------------------------------------------------------
__device__ __forceinline__ float ldc(const float* p) {
  return __hip_atomic_load(p, __ATOMIC_RELAXED, __HIP_MEMORY_SCOPE_AGENT);
}
__device__ __forceinline__ void stc(float* p, float v) {
  __hip_atomic_store(p, v, __ATOMIC_RELAXED, __HIP_MEMORY_SCOPE_AGENT);
}
__device__ __forceinline__ int ldci(const int* p) {
  return __hip_atomic_load(p, __ATOMIC_RELAXED, __HIP_MEMORY_SCOPE_AGENT);
}
__device__ __forceinline__ void stci(int* p, int v) {
  __hip_atomic_store(p, v, __ATOMIC_RELAXED, __HIP_MEMORY_SCOPE_AGENT);
}
__device__ __forceinline__ float2 ldc2(const float* p) {
  union { ull u; float2 f; } c;
  c.u = __hip_atomic_load((const ull*)p, __ATOMIC_RELAXED, __HIP_MEMORY_SCOPE_AGENT);
  return c.f;
}
__device__ __forceinline__ void stc2(float* p, float2 v) {
  union { ull u; float2 f; } c; c.f = v;
  __hip_atomic_store((ull*)p, c.u, __ATOMIC_RELAXED, __HIP_MEMORY_SCOPE_AGENT);
}
__device__ __forceinline__ ull ldcu(const ull* p) {
  return __hip_atomic_load(p, __ATOMIC_RELAXED, __HIP_MEMORY_SCOPE_AGENT);
}
__device__ __forceinline__ void stcu(ull* p, ull v) {
  __hip_atomic_store(p, v, __ATOMIC_RELAXED, __HIP_MEMORY_SCOPE_AGENT);
}

// ---------------------------------------------------------------------------
// Epoch-based two-level grid barrier. Monotonic counters (no resets, no reset
// races), relaxed agent atomics only, NO fences (data coherence comes from the
// coherent accessors above). gen_next = barrier ordinal (1-based), uniform.
// ---------------------------------------------------------------------------
struct GridBar { unsigned cnt[8 * 32]; unsigned mid[32]; unsigned gen[32]; };

__device__ __forceinline__ void gridbar(GridBar* gb, int W, unsigned gen_next) {
  __syncthreads();                 // all waves drain vmem (compiler emits vmcnt(0))
  if (threadIdx.x == 0) {
    const int lane = (int)(blockIdx.x & 7);
    const int rem = W & 7;
    const unsigned nlane = (unsigned)((W >> 3) + (lane < rem ? 1 : 0));
    const unsigned nlanes = (unsigned)(W < 8 ? W : 8);
    unsigned a = __hip_atomic_fetch_add(&gb->cnt[lane * 32], 1u, __ATOMIC_RELAXED,
                                        __HIP_MEMORY_SCOPE_AGENT);
    if (a == nlane * gen_next - 1u) {
      unsigned m = __hip_atomic_fetch_add(&gb->mid[0], 1u, __ATOMIC_RELAXED,
                                          __HIP_MEMORY_SCOPE_AGENT);
      if (m == nlanes * gen_next - 1u)
        __hip_atomic_store(&gb->gen[0], gen_next, __ATOMIC_RELAXED, __HIP_MEMORY_SCOPE_AGENT);
    }
    int i = 0;
    while (__hip_atomic_load(&gb->gen[0], __ATOMIC_RELAXED, __HIP_MEMORY_SCOPE_AGENT)
           < gen_next) {
      if (i < 48) { __builtin_amdgcn_s_sleep(2); ++i; }
      else        { __builtin_amdgcn_s_sleep(16); }
    }
  }
  __syncthreads();
}

__global__ void k_zero(unsigned* w) {
  if (threadIdx.x < sizeof(GridBar) / 4) w[threadIdx.x] = 0;
}

// ---------------------------------------------------------------------------
// GEMM panel core. Numerics identical (strictly ascending-k FMA chain per
// output element). x/out traffic coherent; W (read-only weights) cached.
// wlds pitch WP=68: staging writes 2-way banked (free), reads 16B-aligned.
// ---------------------------------------------------------------------------
template<int SECK>
__device__ __forceinline__ void gemm_panel_m(
    float* __restrict__ xlds,                  // [SECK*32]
    float (* __restrict__ wlds)[2][16 * WP],   // [4 waves][2 buf][16*WP]
    const float* __restrict__ Wrow, int K, int kb0, int nsec,
    const float* __restrict__ xT, float* __restrict__ outP)
{
  const int t = threadIdx.x;
  const int l = t & 63;
  const int wq = t >> 6;
  const int jg = l & 7;
  const int ng = l >> 3;
  const int lrow = l >> 2;
  const int lk4 = (l & 3) * 4;

  float acc[8][4];
#pragma unroll
  for (int i = 0; i < 8; ++i)
#pragma unroll
    for (int q = 0; q < 4; ++q) acc[i][q] = 0.f;

  for (int sec = 0; sec < nsec; ++sec) {
    const int ks = kb0 + sec * SECK;
    __syncthreads();
    {
      const float* src = xT + (size_t)ks * 32;
      for (int i = t * 4; i < SECK * 32; i += 1024) {
        *(float2*)(&xlds[i]) = ldc2(src + i);
        *(float2*)(&xlds[i + 2]) = ldc2(src + i + 2);
      }
    }
    __syncthreads();

    const float* wsrc = Wrow + (size_t)(wq * 64 + lrow) * K + ks + lk4;
    const int nch = SECK / 16;

    float4 wr[4];
#pragma unroll
    for (int p = 0; p < 4; ++p) wr[p] = *(const float4*)(wsrc + (size_t)(p * 16) * K);
#pragma unroll
    for (int p = 0; p < 4; ++p) {
      float* wd = &wlds[wq][0][0];
      wd[(lk4 + 0) * WP + p * 16 + lrow] = wr[p].x;
      wd[(lk4 + 1) * WP + p * 16 + lrow] = wr[p].y;
      wd[(lk4 + 2) * WP + p * 16 + lrow] = wr[p].z;
      wd[(lk4 + 3) * WP + p * 16 + lrow] = wr[p].w;
    }
    int buf = 0;
    for (int c = 0; c < nch; ++c) {
      if (c + 1 < nch) {
#pragma unroll
        for (int p = 0; p < 4; ++p)
          wr[p] = *(const float4*)(wsrc + (size_t)(p * 16) * K + (c + 1) * 16);
      }
      const float* wb = &wlds[wq][buf][0];
      const float* xb = xlds + (size_t)(c * 16) * 32;
#pragma unroll
      for (int k = 0; k < 16; ++k) {
        float4 w0 = *(const float4*)(wb + k * WP + jg * 8);
        float4 w1 = *(const float4*)(wb + k * WP + jg * 8 + 4);
        float4 xv = *(const float4*)(xb + k * 32 + ng * 4);
        acc[0][0] = fmaf(w0.x, xv.x, acc[0][0]); acc[0][1] = fmaf(w0.x, xv.y, acc[0][1]);
        acc[0][2] = fmaf(w0.x, xv.z, acc[0][2]); acc[0][3] = fmaf(w0.x, xv.w, acc[0][3]);
        acc[1][0] = fmaf(w0.y, xv.x, acc[1][0]); acc[1][1] = fmaf(w0.y, xv.y, acc[1][1]);
        acc[1][2] = fmaf(w0.y, xv.z, acc[1][2]); acc[1][3] = fmaf(w0.y, xv.w, acc[1][3]);
        acc[2][0] = fmaf(w0.z, xv.x, acc[2][0]); acc[2][1] = fmaf(w0.z, xv.y, acc[2][1]);
        acc[2][2] = fmaf(w0.z, xv.z, acc[2][2]); acc[2][3] = fmaf(w0.z, xv.w, acc[2][3]);
        acc[3][0] = fmaf(w0.w, xv.x, acc[3][0]); acc[3][1] = fmaf(w0.w, xv.y, acc[3][1]);
        acc[3][2] = fmaf(w0.w, xv.z, acc[3][2]); acc[3][3] = fmaf(w0.w, xv.w, acc[3][3]);
        acc[4][0] = fmaf(w1.x, xv.x, acc[4][0]); acc[4][1] = fmaf(w1.x, xv.y, acc[4][1]);
        acc[4][2] = fmaf(w1.x, xv.z, acc[4][2]); acc[4][3] = fmaf(w1.x, xv.w, acc[4][3]);
        acc[5][0] = fmaf(w1.y, xv.x, acc[5][0]); acc[5][1] = fmaf(w1.y, xv.y, acc[5][1]);
        acc[5][2] = fmaf(w1.y, xv.z, acc[5][2]); acc[5][3] = fmaf(w1.y, xv.w, acc[5][3]);
        acc[6][0] = fmaf(w1.z, xv.x, acc[6][0]); acc[6][1] = fmaf(w1.z, xv.y, acc[6][1]);
        acc[6][2] = fmaf(w1.z, xv.z, acc[6][2]); acc[6][3] = fmaf(w1.z, xv.w, acc[6][3]);
        acc[7][0] = fmaf(w1.w, xv.x, acc[7][0]); acc[7][1] = fmaf(w1.w, xv.y, acc[7][1]);
        acc[7][2] = fmaf(w1.w, xv.z, acc[7][2]); acc[7][3] = fmaf(w1.w, xv.w, acc[7][3]);
      }
      if (c + 1 < nch) {
        float* wd = &wlds[wq][buf ^ 1][0];
#pragma unroll
        for (int p = 0; p < 4; ++p) {
          wd[(lk4 + 0) * WP + p * 16 + lrow] = wr[p].x;
          wd[(lk4 + 1) * WP + p * 16 + lrow] = wr[p].y;
          wd[(lk4 + 2) * WP + p * 16 + lrow] = wr[p].z;
          wd[(lk4 + 3) * WP + p * 16 + lrow] = wr[p].w;
        }
      }
      buf ^= 1;
    }
  }

#pragma unroll
  for (int i = 0; i < 8; ++i) {
    float* dst = outP + (size_t)(wq * 64 + jg * 8 + i) * 32 + ng * 4;
    stc2(dst, make_float2(acc[i][0], acc[i][1]));
    stc2(dst + 2, make_float2(acc[i][2], acc[i][3]));
  }
}

// ---------------------------------------------------------------------------
// Phase bodies (shared between mega-kernel and fallback kernels).
// ---------------------------------------------------------------------------
__device__ __forceinline__ void combine_one(
    int g, const float* __restrict__ gHp, const float* __restrict__ gIp,
    const float* __restrict__ bih, const float* __restrict__ bhh,
    const float* __restrict__ hT, float* __restrict__ h2T)
{
  int n = g & 31, i = g >> 5;
  float gir = bih[i], giz = bih[1024 + i], gin = bih[2048 + i];
#pragma unroll
  for (int s = 0; s < 4; ++s) {
    const float* P = gIp + (size_t)s * (3072 * 32);
    gir += ldc(P + (size_t)i * 32 + n);
    giz += ldc(P + (size_t)(1024 + i) * 32 + n);
    gin += ldc(P + (size_t)(2048 + i) * 32 + n);
  }
  float ghr = bhh[i], ghz = bhh[1024 + i], ghn = bhh[2048 + i];
#pragma unroll
  for (int s = 0; s < 8; ++s) {
    const float* P = gHp + (size_t)s * (3072 * 32);
    ghr += ldc(P + (size_t)i * 32 + n);
    ghz += ldc(P + (size_t)(1024 + i) * 32 + n);
    ghn += ldc(P + (size_t)(2048 + i) * 32 + n);
  }
  float r = 1.f / (1.f + expf(-(gir + ghr)));
  float z = 1.f / (1.f + expf(-(giz + ghz)));
  float nn = tanhf(gin + r * ghn);
  stc(h2T + g, (1.f - z) * nn + z * ldc(hT + g));
}

__device__ __forceinline__ void reduce_one(
    int bx, float (* __restrict__ tile)[33],
    const float* __restrict__ logitsP, const float* __restrict__ bout,
    float* __restrict__ logitsN, float* __restrict__ lsePart, int NS)
{
  const int t = threadIdx.x;
  const int j0 = bx * 64;

  {
    const int n = t & 31;
    const int jb = (t >> 5) * 8;
    float v[8];
#pragma unroll
    for (int i = 0; i < 8; ++i) v[i] = bout[j0 + jb + i];
    for (int s = 0; s < NS; ++s) {
      const float* P = logitsP + (size_t)s * (NV * 32) + (size_t)(j0 + jb) * 32 + n;
#pragma unroll
      for (int i = 0; i < 8; ++i) v[i] += ldc(P + (size_t)i * 32);
    }
#pragma unroll
    for (int i = 0; i < 8; ++i) tile[jb + i][n] = v[i];
  }
  __syncthreads();
  {
    const int jl = t & 63;
    const int wq = t >> 6;
#pragma unroll
    for (int q = 0; q < 8; ++q) {
      const int nn = wq * 8 + q;
      float val = tile[jl][nn];
      stc(logitsN + (size_t)nn * NV + j0 + jl, val);
      float m = val;
      m = fmaxf(m, __shfl_xor(m, 1, 64));
      m = fmaxf(m, __shfl_xor(m, 2, 64));
      m = fmaxf(m, __shfl_xor(m, 4, 64));
      m = fmaxf(m, __shfl_xor(m, 8, 64));
      m = fmaxf(m, __shfl_xor(m, 16, 64));
      m = fmaxf(m, __shfl_xor(m, 32, 64));
      float sx = expf(val - m);
      sx += __shfl_xor(sx, 1, 64);
      sx += __shfl_xor(sx, 2, 64);
      sx += __shfl_xor(sx, 4, 64);
      sx += __shfl_xor(sx, 8, 64);
      sx += __shfl_xor(sx, 16, 64);
      sx += __shfl_xor(sx, 32, 64);
      if (jl == 0)
        stc2(lsePart + (size_t)bx * 64 + nn * 2, make_float2(m, sx));
    }
  }
}

struct TAsh { float pm[32][8]; float ps[32][8]; float A[8]; ull wm[4]; };

__device__ __forceinline__ void topkA_one(
    int b, int c, TAsh* S,
    const float* __restrict__ logitsN, const float* __restrict__ lsePart,
    const float* __restrict__ prev_vals, const int* __restrict__ prev_tok,
    int eos, ull* __restrict__ top8A, int mode)
{
  const int t = threadIdx.x;

  // phase 1: finish logsumexp over 500 partials
  {
    const int n8 = t & 7;
    const int grp = t >> 3;
    float m = -3.0e38f, s = 0.f;
    for (int p = grp; p < 500; p += 32) {
      float2 q = ldc2(lsePart + (size_t)p * 64 + (b * 8 + n8) * 2);
      float Mx = fmaxf(m, q.x);
      s = s * expf(m - Mx) + q.y * expf(q.x - Mx);
      m = Mx;
    }
    S->pm[grp][n8] = m; S->ps[grp][n8] = s;
    __syncthreads();
    for (int off2 = 16; off2 >= 1; off2 >>= 1) {
      if (grp < off2) {
        float m1 = S->pm[grp][n8], s1 = S->ps[grp][n8];
        float m2 = S->pm[grp + off2][n8], s2 = S->ps[grp + off2][n8];
        float Mx = fmaxf(m1, m2);
        S->pm[grp][n8] = Mx;
        S->ps[grp][n8] = s1 * expf(m1 - Mx) + s2 * expf(m2 - Mx);
      }
      __syncthreads();
    }
    if (t < 8) S->A[t] = S->pm[0][t] + logf(S->ps[0][t]);
    __syncthreads();
  }

  ull t8[8];
#pragma unroll
  for (int j = 0; j < 8; ++j) t8[j] = 0ULL;

  if (mode == 1) {
    const int kb = c >> 2;
    const int v0 = (c & 3) * 8000;
    const bool fin = (ldci(prev_tok + b * 8 + kb) == eos);
    const float add = ldc(prev_vals + b * 8 + kb) - S->A[kb];
    const float* row = logitsN + (size_t)(b * 8 + kb) * NV;
    for (int v = v0 + t; v < v0 + 8000; v += 256) {
      float val;
      if (fin) val = (v == eos) ? 0.f : -1e30f;
      else val = ldc(row + v) + add;
      ull key = packkey(val, (unsigned)(kb * NV + v));
      if (key > t8[7]) {
        t8[7] = key;
#pragma unroll
        for (int q = 7; q >= 1; --q) {
          ull hi = umax64(t8[q - 1], t8[q]);
          ull lo = umin64(t8[q - 1], t8[q]);
          t8[q - 1] = hi; t8[q] = lo;
        }
      }
    }
  } else {
    const int v0 = c * 1000;
    const float add = -S->A[0];
    const float* row = logitsN + (size_t)(b * 8) * NV;
    for (int v = v0 + t; v < v0 + 1000; v += 256) {
      float val = ldc(row + v) + add;
      ull key = packkey(val, (unsigned)v);
      if (key > t8[7]) {
        t8[7] = key;
#pragma unroll
        for (int q = 7; q >= 1; --q) {
          ull hi = umax64(t8[q - 1], t8[q]);
          ull lo = umin64(t8[q - 1], t8[q]);
          t8[q - 1] = hi; t8[q] = lo;
        }
      }
    }
  }

  // 8-round exact extraction (keys unique)
  int pi = 0;
  for (int r = 0; r < 8; ++r) {
    ull cand = (pi < 8) ? t8[pi] : 0ULL;
#pragma unroll
    for (int off = 1; off < 64; off <<= 1) cand = umax64(cand, __shfl_xor(cand, off, 64));
    if ((t & 63) == 0) S->wm[t >> 6] = cand;
    __syncthreads();
    ull win = umax64(umax64(S->wm[0], S->wm[1]), umax64(S->wm[2], S->wm[3]));
    if (pi < 8 && t8[pi] == win) ++pi;
    if (t == 0) stcu(top8A + ((size_t)b * 32 + c) * 8 + r, win);
    __syncthreads();
  }
}

struct TBsh { ull wm[4]; float vals8[8]; int tok8[8]; int which8[8]; };

__device__ __forceinline__ void topkB_one(
    int b, TBsh* S, const ull* __restrict__ top8A,
    float* __restrict__ prev_vals, int* __restrict__ prev_tok,
    const float* __restrict__ lp_src, float* __restrict__ lp_dst,
    const int* __restrict__ tok_src, int* __restrict__ tok_dst,
    const float* __restrict__ h2T, float* __restrict__ hT,
    const float* __restrict__ emb, float* __restrict__ embX,
    int step, int mode)
{
  const int t = threadIdx.x;

  ull mykey = ldcu(top8A + (size_t)b * 256 + t);
  int done = 0;
  for (int r = 0; r < 8; ++r) {
    ull cand = done ? 0ULL : mykey;
#pragma unroll
    for (int off = 1; off < 64; off <<= 1) cand = umax64(cand, __shfl_xor(cand, off, 64));
    if ((t & 63) == 0) S->wm[t >> 6] = cand;
    __syncthreads();
    ull win = umax64(umax64(S->wm[0], S->wm[1]), umax64(S->wm[2], S->wm[3]));
    if (!done && mykey == win) done = 1;
    if (t == 0) {
      unsigned idx = 0xFFFFFFFFu - (unsigned)(win & 0xFFFFFFFFull);
      unsigned u = (unsigned)(win >> 32);
      u = (u >> 31) ? (u ^ 0x80000000u) : ~u;
      S->vals8[r] = __uint_as_float(u);
      if (mode == 1) { S->tok8[r] = (int)(idx % NV); S->which8[r] = (int)(idx / NV); }
      else { S->tok8[r] = (int)idx; S->which8[r] = r; }
    }
    __syncthreads();
  }

  if (t < 8) {
    stc(prev_vals + b * 8 + t, S->vals8[t]);
    stci(prev_tok + b * 8 + t, S->tok8[t]);
  }
  for (int idx = t; idx < 512; idx += 256) {
    int j = idx >> 6;
    int tt = idx & 63;
    float lv; int tv;
    if (tt == step) { lv = S->vals8[j]; tv = S->tok8[j]; }
    else if (mode == 0) { lv = 0.f; tv = 0; }
    else {
      int w = S->which8[j];
      lv = ldc(lp_src + b * 512 + w * 64 + tt);
      tv = ldci(tok_src + b * 512 + w * 64 + tt);
    }
    stc(lp_dst + b * 512 + idx, lv);
    stci(tok_dst + b * 512 + idx, tv);
  }
  for (int idx = t; idx < 8192; idx += 256) {
    int kk = idx >> 3;
    int j = idx & 7;
    stc(hT + kk * 32 + b * 8 + j, ldc(h2T + kk * 32 + b * 8 + S->which8[j]));
  }
  {
    int j = t >> 5;
    int kbase = (t & 31) * 16;
    const float* src = emb + (size_t)S->tok8[j] * EMB + kbase;
#pragma unroll
    for (int q = 0; q < 4; ++q) {
      float4 v = *(const float4*)(src + 4 * q);
      stc(embX + (kbase + 4 * q + 0) * 32 + b * 8 + j, v.x);
      stc(embX + (kbase + 4 * q + 1) * 32 + b * 8 + j, v.y);
      stc(embX + (kbase + 4 * q + 2) * 32 + b * 8 + j, v.z);
      stc(embX + (kbase + 4 * q + 3) * 32 + b * 8 + j, v.w);
    }
  }
}

// ---------------------------------------------------------------------------
// Mega-kernel: entire 64-step loop in one cooperative launch. W=256 (1/CU).
// ---------------------------------------------------------------------------
union MegaLDS {
  struct { float x[128 * 32]; float w[4][2][16 * WP]; } gp;  // 50 KiB
  float tile[64][33];
  TAsh ta;
  TBsh tb;
};

struct MegaArgs {
  const float* encoded; const float* embedding;
  const float* Wih; const float* Whh; const float* bih; const float* bhh;
  const float* Wout; const float* bout;
  const int* bosp; const int* eosp;
  float* hT; float* h2T; float* embX; float* gHp; float* gIp;
  float* logitsN; float* lsePart; ull* top8A;
  float* prev_vals; int* prev_tok;
  float* lp0; float* lp1; int* tok0; int* tok1;
  float* logitsP; int NS;
  GridBar* gb; float* outp;
};

__global__ __launch_bounds__(256, 2) void k_mega(MegaArgs a)
{
  __shared__ MegaLDS L;
  const int W = (int)gridDim.x;
  const int bid = (int)blockIdx.x;
  const int t = (int)threadIdx.x;
  const int KperS = 1024 / a.NS;
  const int NPANL = 125 * a.NS;
  unsigned bgen = 0;

  // prep: hT / embX for step 0
  for (int g = bid * 256 + t; g < 49152; g += W * 256) {
    if (g < 32768) {
      int k = g >> 5, n = g & 31;
      stc(a.hT + g, a.encoded[(n >> 3) * HID + k]);
    } else {
      int g2 = g - 32768;
      int k = g2 >> 5;
      stc(a.embX + g2, a.embedding[(size_t)(*a.bosp) * EMB + k]);
    }
  }
  gridbar(a.gb, W, ++bgen);
  const int eos = *a.eosp;

  for (int st = 0; st < NT; ++st) {
    // ---- gates (144 panels) ----
    for (int p = bid; p < 144; p += W) {
      if (p < 96) {
        int jt = p % 12, s = p / 12;
        gemm_panel_m<128>(L.gp.x, L.gp.w, a.Whh + (size_t)jt * 256 * HID, HID, s * 128, 1,
                          a.hT, a.gHp + (size_t)s * (3072 * 32) + (size_t)jt * 256 * 32);
      } else {
        int r = p - 96, jt = r % 12, s = r / 12;
        gemm_panel_m<128>(L.gp.x, L.gp.w, a.Wih + (size_t)jt * 256 * EMB, EMB, s * 128, 1,
                          a.embX, a.gIp + (size_t)s * (3072 * 32) + (size_t)jt * 256 * 32);
      }
    }
    gridbar(a.gb, W, ++bgen);

    // ---- combine -> h2T ----
    for (int g = bid * 256 + t; g < 32768; g += W * 256)
      combine_one(g, a.gHp, a.gIp, a.bih, a.bhh, a.hT, a.h2T);
    gridbar(a.gb, W, ++bgen);

    // ---- logits (125*NS panels) ----
    for (int p = bid; p < NPANL; p += W) {
      int jt = p % 125, s = p / 125;
      gemm_panel_m<128>(L.gp.x, L.gp.w, a.Wout + (size_t)jt * 256 * HID, HID, s * KperS,
                        KperS / 128, a.h2T,
                        a.logitsP + (size_t)s * (NV * 32) + (size_t)jt * 256 * 32);
    }
    gridbar(a.gb, W, ++bgen);

    // ---- reduce: sum slabs + bias, transpose, lse partials ----
    for (int c = bid; c < 500; c += W) {
      reduce_one(c, L.tile, a.logitsP, a.bout, a.logitsN, a.lsePart, a.NS);
      __syncthreads();
    }
    gridbar(a.gb, W, ++bgen);

    const int mode = (st == 0) ? 0 : 1;

    // ---- topkA (128 items) ----
    for (int it = bid; it < 128; it += W)
      topkA_one(it >> 5, it & 31, &L.ta, a.logitsN, a.lsePart, a.prev_vals, a.prev_tok,
                eos, a.top8A, mode);
    gridbar(a.gb, W, ++bgen);

    // ---- topkB (4 items) ----
    {
      float* lps = (st & 1) ? a.lp0 : a.lp1;
      float* lpd = (st & 1) ? a.lp1 : a.lp0;
      int* tks = (st & 1) ? a.tok0 : a.tok1;
      int* tkd = (st & 1) ? a.tok1 : a.tok0;
      for (int b = bid; b < NB; b += W)
        topkB_one(b, &L.tb, a.top8A, a.prev_vals, a.prev_tok, lps, lpd, tks, tkd,
                  a.h2T, a.hT, a.embedding, a.embX, st, mode);
    }
    gridbar(a.gb, W, ++bgen);
  }

  // final: out = [lp_hist, tok_hist as float]
  for (int g = bid * 256 + t; g < 4096; g += W * 256) {
    if (g < 2048) a.outp[g] = ldc(a.lp1 + g);
    else a.outp[g] = (float)ldci(a.tok1 + g - 2048);
  }
}

// ---------------------------------------------------------------------------
// Fallback kernels (original multi-launch path), sharing the same bodies.
// ---------------------------------------------------------------------------
__global__ void k_prep(const float* __restrict__ encoded, const float* __restrict__ emb,
                       const int* __restrict__ bosp,
                       float* __restrict__ hT, float* __restrict__ embX)
{
  int g = blockIdx.x * 256 + threadIdx.x;   // 49152
  if (g < 32768) {
    int k = g >> 5, n = g & 31;
    stc(hT + g, encoded[(n >> 3) * HID + k]);
  } else {
    int g2 = g - 32768;
    int k = g2 >> 5;
    stc(embX + g2, emb[(size_t)(*bosp) * EMB + k]);
  }
}

__global__ __launch_bounds__(256, 2) void k_gates(
    const float* __restrict__ Wih, const float* __restrict__ Whh,
    const float* __restrict__ embX, const float* __restrict__ hT,
    float* __restrict__ gHp, float* __restrict__ gIp)
{
  __shared__ float xlds[128 * 32];
  __shared__ float wlds[4][2][16 * WP];
  const int bx = blockIdx.x;
  if (bx < 96) {
    const int jt = bx % 12, s = bx / 12;
    gemm_panel_m<128>(xlds, wlds, Whh + (size_t)jt * 256 * HID, HID, s * 128, 1, hT,
                      gHp + (size_t)s * (3072 * 32) + (size_t)jt * 256 * 32);
  } else {
    const int r = bx - 96;
    const int jt = r % 12, s = r / 12;
    gemm_panel_m<128>(xlds, wlds, Wih + (size_t)jt * 256 * EMB, EMB, s * 128, 1, embX,
                      gIp + (size_t)s * (3072 * 32) + (size_t)jt * 256 * 32);
  }
}

__global__ __launch_bounds__(256) void k_combine(
    const float* __restrict__ gHp, const float* __restrict__ gIp,
    const float* __restrict__ bih, const float* __restrict__ bhh,
    const float* __restrict__ hT, float* __restrict__ h2T)
{
  int g = blockIdx.x * 256 + threadIdx.x;   // 32768
  combine_one(g, gHp, gIp, bih, bhh, hT, h2T);
}

__global__ __launch_bounds__(256, 2) void k_logits(
    const float* __restrict__ Wout, const float* __restrict__ h2T,
    float* __restrict__ logitsP, int NS)
{
  __shared__ float xlds[128 * 32];
  __shared__ float wlds[4][2][16 * WP];
  const int jt = blockIdx.x % 125;
  const int s = blockIdx.x / 125;
  const int KperS = 1024 / NS;
  gemm_panel_m<128>(xlds, wlds, Wout + (size_t)jt * 256 * HID, HID, s * KperS, KperS / 128,
                    h2T, logitsP + (size_t)s * (NV * 32) + (size_t)jt * 256 * 32);
}

__global__ __launch_bounds__(256) void k_reduce(
    const float* __restrict__ logitsP, const float* __restrict__ bout,
    float* __restrict__ logitsN, float* __restrict__ lsePart, int NS)
{
  __shared__ float tile[64][33];
  reduce_one(blockIdx.x, tile, logitsP, bout, logitsN, lsePart, NS);
}

__global__ __launch_bounds__(256) void k_topkA(
    const float* __restrict__ logitsN, const float* __restrict__ lsePart,
    const float* __restrict__ prev_vals, const int* __restrict__ prev_tok,
    const int* __restrict__ eosp, ull* __restrict__ top8A, int mode)
{
  __shared__ TAsh S;
  topkA_one(blockIdx.x >> 5, blockIdx.x & 31, &S, logitsN, lsePart, prev_vals, prev_tok,
            *eosp, top8A, mode);
}

__global__ __launch_bounds__(256) void k_topkB(
    const ull* __restrict__ top8A,
    float* __restrict__ prev_vals, int* __restrict__ prev_tok,
    const float* __restrict__ lp_src, float* __restrict__ lp_dst,
    const int* __restrict__ tok_src, int* __restrict__ tok_dst,
    const float* __restrict__ h2T, float* __restrict__ hT,
    const float* __restrict__ emb, float* __restrict__ embX,
    int step, int mode)
{
  __shared__ TBsh S;
  topkB_one(blockIdx.x, &S, top8A, prev_vals, prev_tok, lp_src, lp_dst, tok_src, tok_dst,
            h2T, hT, emb, embX, step, mode);
}

__global__ void k_final(const float* __restrict__ lp_hist, const int* __restrict__ tok_hist,
                        float* __restrict__ out)
{
  int g = blockIdx.x * 256 + threadIdx.x;   // 4096
  if (g < 2048) out[g] = ldc(lp_hist + g);
  else out[g] = (float)ldci(tok_hist + g - 2048);
}

extern "C" void kernel_launch(void* const* d_in, const int* in_sizes, int n_in,
                              void* d_out, int out_size, void* d_ws, size_t ws_size,
                              hipStream_t stream)
{
  (void)in_sizes; (void)n_in; (void)out_size;
  const float* encoded   = (const float*)d_in[0];
  const float* embedding = (const float*)d_in[1];
  const float* Wih       = (const float*)d_in[2];
  const float* Whh       = (const float*)d_in[3];
  const float* bih       = (const float*)d_in[4];
  const float* bhh       = (const float*)d_in[5];
  const float* Wout      = (const float*)d_in[6];
  const float* bout      = (const float*)d_in[7];
  const int*   bosp      = (const int*)d_in[8];
  const int*   eosp      = (const int*)d_in[9];

  char* p = (char*)d_ws;
  size_t off = 0;
  auto ALLOC = [&](size_t bytes) -> void* {
    void* r = p + off;
    off += (bytes + 255) & ~(size_t)255;
    return r;
  };
  float* hT        = (float*)ALLOC((size_t)HID * 32 * 4);
  float* h2T       = (float*)ALLOC((size_t)HID * 32 * 4);
  float* embX      = (float*)ALLOC((size_t)EMB * 32 * 4);
  float* gHp       = (float*)ALLOC((size_t)8 * 3072 * 32 * 4);   // 3.15 MB
  float* gIp       = (float*)ALLOC((size_t)4 * 3072 * 32 * 4);   // 1.57 MB
  // logitsN overlays gHp+gIp (consumed by combine before reduce writes it;
  // gates rewrites next step only after topkA has consumed logitsN).
  float* logitsN   = gHp;
  float* lsePart   = (float*)ALLOC((size_t)500 * 64 * 4);
  ull*   top8A     = (ull*)ALLOC((size_t)NB * 32 * 8 * 8);
  float* prev_vals = (float*)ALLOC(32 * 4);
  int*   prev_tok  = (int*)ALLOC(32 * 4);
  float* lp0       = (float*)ALLOC(2048 * 4);
  float* lp1       = (float*)ALLOC(2048 * 4);
  int*   tok0      = (int*)ALLOC(2048 * 4);
  int*   tok1      = (int*)ALLOC(2048 * 4);
  GridBar* gb      = (GridBar*)ALLOC(sizeof(GridBar));

  int NS = 4;
  if (off + (size_t)4 * NV * 32 * 4 > ws_size) NS = 2;
  if (off + (size_t)2 * NV * 32 * 4 > ws_size) NS = 1;
  float* logitsP = (float*)ALLOC((size_t)NS * NV * 32 * 4);

  // ---- preferred path: one cooperative launch for the whole loop ----
  k_zero<<<1, 512, 0, stream>>>((unsigned*)gb);

  MegaArgs ma;
  ma.encoded = encoded; ma.embedding = embedding;
  ma.Wih = Wih; ma.Whh = Whh; ma.bih = bih; ma.bhh = bhh;
  ma.Wout = Wout; ma.bout = bout; ma.bosp = bosp; ma.eosp = eosp;
  ma.hT = hT; ma.h2T = h2T; ma.embX = embX; ma.gHp = gHp; ma.gIp = gIp;
  ma.logitsN = logitsN; ma.lsePart = lsePart; ma.top8A = top8A;
  ma.prev_vals = prev_vals; ma.prev_tok = prev_tok;
  ma.lp0 = lp0; ma.lp1 = lp1; ma.tok0 = tok0; ma.tok1 = tok1;
  ma.logitsP = logitsP; ma.NS = NS; ma.gb = gb; ma.outp = (float*)d_out;

  const int W = 256;  // 1 WG/CU: cheap barrier, all phases grid-stride
  void* kargs[] = { &ma };
  hipError_t e = hipLaunchCooperativeKernel(k_mega, dim3(W), dim3(256), kargs, 0, stream);
  if (e == hipSuccess) return;
  (void)hipGetLastError();  // clear error state; fall back to multi-launch path

  // ---- fallback: original (proven) multi-launch sequence ----
  k_prep<<<192, 256, 0, stream>>>(encoded, embedding, bosp, hT, embX);
  for (int t = 0; t < NT; ++t) {
    k_gates<<<144, 256, 0, stream>>>(Wih, Whh, embX, hT, gHp, gIp);
    k_combine<<<128, 256, 0, stream>>>(gHp, gIp, bih, bhh, hT, h2T);
    k_logits<<<125 * NS, 256, 0, stream>>>(Wout, h2T, logitsP, NS);
    k_reduce<<<500, 256, 0, stream>>>(logitsP, bout, logitsN, lsePart, NS);
    const int mode = (t == 0) ? 0 : 1;
    k_topkA<<<128, 256, 0, stream>>>(logitsN, lsePart, prev_vals, prev_tok, eosp, top8A, mode);
    float* lps = (t & 1) ? lp0 : lp1;
    float* lpd = (t & 1) ? lp1 : lp0;
    int*   tks = (t & 1) ? tok0 : tok1;
    int*   tkd = (t & 1) ? tok1 : tok0;
    k_topkB<<<NB, 256, 0, stream>>>(top8A, prev_vals, prev_tok, lps, lpd, tks, tkd,
                                    h2T, hT, embedding, embX, t, mode);
  }
  k_final<<<16, 256, 0, stream>>>(lp1, tok1, (float*)d_out);
}

// Round 4
// 9209.271 us; speedup vs baseline: 1.2890x; 1.0424x over previous
//
#include <hip/hip_runtime.h>

typedef unsigned long long ull;

#define EMB 512
#define HID 1024
#define NV  32000
#define NB  4
#define NT  64
#define WP  68   // wlds pitch in floats: 16B-aligned reads, 2-way (free) bank conflicts

__device__ __forceinline__ ull umax64(ull a, ull b) { return a > b ? a : b; }
__device__ __forceinline__ ull umin64(ull a, ull b) { return a < b ? a : b; }

// Total-order key: larger value first, ties -> lower index (matches jax.lax.top_k)
__device__ __forceinline__ ull packkey(float v, unsigned idx) {
  unsigned u = __float_as_uint(v);
  u ^= (u >> 31) ? 0xFFFFFFFFu : 0x80000000u;
  return ((ull)u << 32) | (ull)(0xFFFFFFFFu - idx);
}

// ---------------------------------------------------------------------------
// Coherent (agent-scope, relaxed) accessors for cross-phase intermediates.
// ---------------------------------------------------------------------------
__device__ __forceinline__ float ldc(const float* p) {
  return __hip_atomic_load(p, __ATOMIC_RELAXED, __HIP_MEMORY_SCOPE_AGENT);
}
__device__ __forceinline__ void stc(float* p, float v) {
  __hip_atomic_store(p, v, __ATOMIC_RELAXED, __HIP_MEMORY_SCOPE_AGENT);
}
__device__ __forceinline__ int ldci(const int* p) {
  return __hip_atomic_load(p, __ATOMIC_RELAXED, __HIP_MEMORY_SCOPE_AGENT);
}
__device__ __forceinline__ void stci(int* p, int v) {
  __hip_atomic_store(p, v, __ATOMIC_RELAXED, __HIP_MEMORY_SCOPE_AGENT);
}
__device__ __forceinline__ float2 ldc2(const float* p) {
  union { ull u; float2 f; } c;
  c.u = __hip_atomic_load((const ull*)p, __ATOMIC_RELAXED, __HIP_MEMORY_SCOPE_AGENT);
  return c.f;
}
__device__ __forceinline__ void stc2(float* p, float2 v) {
  union { ull u; float2 f; } c; c.f = v;
  __hip_atomic_store((ull*)p, c.u, __ATOMIC_RELAXED, __HIP_MEMORY_SCOPE_AGENT);
}
__device__ __forceinline__ ull ldcu(const ull* p) {
  return __hip_atomic_load(p, __ATOMIC_RELAXED, __HIP_MEMORY_SCOPE_AGENT);
}
__device__ __forceinline__ void stcu(ull* p, ull v) {
  __hip_atomic_store(p, v, __ATOMIC_RELAXED, __HIP_MEMORY_SCOPE_AGENT);
}

// ---------------------------------------------------------------------------
// Epoch-based two-level grid barrier. Monotonic counters, relaxed agent
// atomics only, NO fences. gen_next = barrier ordinal (1-based), uniform.
// ---------------------------------------------------------------------------
struct GridBar { unsigned cnt[8 * 32]; unsigned mid[32]; unsigned gen[32]; };

__device__ __forceinline__ void gridbar(GridBar* gb, int W, unsigned gen_next) {
  __syncthreads();
  if (threadIdx.x == 0) {
    const int lane = (int)(blockIdx.x & 7);
    const int rem = W & 7;
    const unsigned nlane = (unsigned)((W >> 3) + (lane < rem ? 1 : 0));
    const unsigned nlanes = (unsigned)(W < 8 ? W : 8);
    unsigned a = __hip_atomic_fetch_add(&gb->cnt[lane * 32], 1u, __ATOMIC_RELAXED,
                                        __HIP_MEMORY_SCOPE_AGENT);
    if (a == nlane * gen_next - 1u) {
      unsigned m = __hip_atomic_fetch_add(&gb->mid[0], 1u, __ATOMIC_RELAXED,
                                          __HIP_MEMORY_SCOPE_AGENT);
      if (m == nlanes * gen_next - 1u)
        __hip_atomic_store(&gb->gen[0], gen_next, __ATOMIC_RELAXED, __HIP_MEMORY_SCOPE_AGENT);
    }
    int i = 0;
    while (__hip_atomic_load(&gb->gen[0], __ATOMIC_RELAXED, __HIP_MEMORY_SCOPE_AGENT)
           < gen_next) {
      if (i < 48) { __builtin_amdgcn_s_sleep(2); ++i; }
      else        { __builtin_amdgcn_s_sleep(16); }
    }
  }
  __syncthreads();
}

__global__ void k_zero(unsigned* w) {
  if (threadIdx.x < sizeof(GridBar) / 4) w[threadIdx.x] = 0;
}

// ---------------------------------------------------------------------------
// GEMM panel core. Numerics identical (strictly ascending-k FMA chain per
// output element).
// ---------------------------------------------------------------------------
template<int SECK>
__device__ __forceinline__ void gemm_panel_m(
    float* __restrict__ xlds,                  // [SECK*32]
    float (* __restrict__ wlds)[2][16 * WP],   // [4 waves][2 buf][16*WP]
    const float* __restrict__ Wrow, int K, int kb0, int nsec,
    const float* __restrict__ xT, float* __restrict__ outP)
{
  const int t = threadIdx.x;
  const int l = t & 63;
  const int wq = t >> 6;
  const int jg = l & 7;
  const int ng = l >> 3;
  const int lrow = l >> 2;
  const int lk4 = (l & 3) * 4;

  float acc[8][4];
#pragma unroll
  for (int i = 0; i < 8; ++i)
#pragma unroll
    for (int q = 0; q < 4; ++q) acc[i][q] = 0.f;

  for (int sec = 0; sec < nsec; ++sec) {
    const int ks = kb0 + sec * SECK;
    __syncthreads();
    {
      const float* src = xT + (size_t)ks * 32;
      for (int i = t * 4; i < SECK * 32; i += 1024) {
        *(float2*)(&xlds[i]) = ldc2(src + i);
        *(float2*)(&xlds[i + 2]) = ldc2(src + i + 2);
      }
    }
    __syncthreads();

    const float* wsrc = Wrow + (size_t)(wq * 64 + lrow) * K + ks + lk4;
    const int nch = SECK / 16;

    float4 wr[4];
#pragma unroll
    for (int p = 0; p < 4; ++p) wr[p] = *(const float4*)(wsrc + (size_t)(p * 16) * K);
#pragma unroll
    for (int p = 0; p < 4; ++p) {
      float* wd = &wlds[wq][0][0];
      wd[(lk4 + 0) * WP + p * 16 + lrow] = wr[p].x;
      wd[(lk4 + 1) * WP + p * 16 + lrow] = wr[p].y;
      wd[(lk4 + 2) * WP + p * 16 + lrow] = wr[p].z;
      wd[(lk4 + 3) * WP + p * 16 + lrow] = wr[p].w;
    }
    int buf = 0;
    for (int c = 0; c < nch; ++c) {
      if (c + 1 < nch) {
#pragma unroll
        for (int p = 0; p < 4; ++p)
          wr[p] = *(const float4*)(wsrc + (size_t)(p * 16) * K + (c + 1) * 16);
      }
      const float* wb = &wlds[wq][buf][0];
      const float* xb = xlds + (size_t)(c * 16) * 32;
#pragma unroll
      for (int k = 0; k < 16; ++k) {
        float4 w0 = *(const float4*)(wb + k * WP + jg * 8);
        float4 w1 = *(const float4*)(wb + k * WP + jg * 8 + 4);
        float4 xv = *(const float4*)(xb + k * 32 + ng * 4);
        acc[0][0] = fmaf(w0.x, xv.x, acc[0][0]); acc[0][1] = fmaf(w0.x, xv.y, acc[0][1]);
        acc[0][2] = fmaf(w0.x, xv.z, acc[0][2]); acc[0][3] = fmaf(w0.x, xv.w, acc[0][3]);
        acc[1][0] = fmaf(w0.y, xv.x, acc[1][0]); acc[1][1] = fmaf(w0.y, xv.y, acc[1][1]);
        acc[1][2] = fmaf(w0.y, xv.z, acc[1][2]); acc[1][3] = fmaf(w0.y, xv.w, acc[1][3]);
        acc[2][0] = fmaf(w0.z, xv.x, acc[2][0]); acc[2][1] = fmaf(w0.z, xv.y, acc[2][1]);
        acc[2][2] = fmaf(w0.z, xv.z, acc[2][2]); acc[2][3] = fmaf(w0.z, xv.w, acc[2][3]);
        acc[3][0] = fmaf(w0.w, xv.x, acc[3][0]); acc[3][1] = fmaf(w0.w, xv.y, acc[3][1]);
        acc[3][2] = fmaf(w0.w, xv.z, acc[3][2]); acc[3][3] = fmaf(w0.w, xv.w, acc[3][3]);
        acc[4][0] = fmaf(w1.x, xv.x, acc[4][0]); acc[4][1] = fmaf(w1.x, xv.y, acc[4][1]);
        acc[4][2] = fmaf(w1.x, xv.z, acc[4][2]); acc[4][3] = fmaf(w1.x, xv.w, acc[4][3]);
        acc[5][0] = fmaf(w1.y, xv.x, acc[5][0]); acc[5][1] = fmaf(w1.y, xv.y, acc[5][1]);
        acc[5][2] = fmaf(w1.y, xv.z, acc[5][2]); acc[5][3] = fmaf(w1.y, xv.w, acc[5][3]);
        acc[6][0] = fmaf(w1.z, xv.x, acc[6][0]); acc[6][1] = fmaf(w1.z, xv.y, acc[6][1]);
        acc[6][2] = fmaf(w1.z, xv.z, acc[6][2]); acc[6][3] = fmaf(w1.z, xv.w, acc[6][3]);
        acc[7][0] = fmaf(w1.w, xv.x, acc[7][0]); acc[7][1] = fmaf(w1.w, xv.y, acc[7][1]);
        acc[7][2] = fmaf(w1.w, xv.z, acc[7][2]); acc[7][3] = fmaf(w1.w, xv.w, acc[7][3]);
      }
      if (c + 1 < nch) {
        float* wd = &wlds[wq][buf ^ 1][0];
#pragma unroll
        for (int p = 0; p < 4; ++p) {
          wd[(lk4 + 0) * WP + p * 16 + lrow] = wr[p].x;
          wd[(lk4 + 1) * WP + p * 16 + lrow] = wr[p].y;
          wd[(lk4 + 2) * WP + p * 16 + lrow] = wr[p].z;
          wd[(lk4 + 3) * WP + p * 16 + lrow] = wr[p].w;
        }
      }
      buf ^= 1;
    }
  }

#pragma unroll
  for (int i = 0; i < 8; ++i) {
    float* dst = outP + (size_t)(wq * 64 + jg * 8 + i) * 32 + ng * 4;
    stc2(dst, make_float2(acc[i][0], acc[i][1]));
    stc2(dst + 2, make_float2(acc[i][2], acc[i][3]));
  }
}

// ---------------------------------------------------------------------------
// Phase bodies. Loads batched into registers first (independent issue; atomics
// are not compiler-pipelined across uses), then summed in the ORIGINAL order.
// ---------------------------------------------------------------------------
__device__ __forceinline__ void combine_one(
    int g, const float* __restrict__ gHp, const float* __restrict__ gIp,
    const float* __restrict__ bih, const float* __restrict__ bhh,
    const float* __restrict__ hT, float* __restrict__ h2T)
{
  int n = g & 31, i = g >> 5;
  float pI[4][3];
#pragma unroll
  for (int s = 0; s < 4; ++s) {
    const float* P = gIp + (size_t)s * (3072 * 32);
    pI[s][0] = ldc(P + (size_t)i * 32 + n);
    pI[s][1] = ldc(P + (size_t)(1024 + i) * 32 + n);
    pI[s][2] = ldc(P + (size_t)(2048 + i) * 32 + n);
  }
  float pH[8][3];
#pragma unroll
  for (int s = 0; s < 8; ++s) {
    const float* P = gHp + (size_t)s * (3072 * 32);
    pH[s][0] = ldc(P + (size_t)i * 32 + n);
    pH[s][1] = ldc(P + (size_t)(1024 + i) * 32 + n);
    pH[s][2] = ldc(P + (size_t)(2048 + i) * 32 + n);
  }
  float hv = ldc(hT + g);
  float gir = bih[i], giz = bih[1024 + i], gin = bih[2048 + i];
#pragma unroll
  for (int s = 0; s < 4; ++s) { gir += pI[s][0]; giz += pI[s][1]; gin += pI[s][2]; }
  float ghr = bhh[i], ghz = bhh[1024 + i], ghn = bhh[2048 + i];
#pragma unroll
  for (int s = 0; s < 8; ++s) { ghr += pH[s][0]; ghz += pH[s][1]; ghn += pH[s][2]; }
  float r = 1.f / (1.f + expf(-(gir + ghr)));
  float z = 1.f / (1.f + expf(-(giz + ghz)));
  float nn = tanhf(gin + r * ghn);
  stc(h2T + g, (1.f - z) * nn + z * hv);
}

__device__ __forceinline__ void reduce_one(
    int bx, float (* __restrict__ tile)[33],
    const float* __restrict__ logitsP, const float* __restrict__ bout,
    float* __restrict__ logitsN, float* __restrict__ lsePart, int NS)
{
  const int t = threadIdx.x;
  const int j0 = bx * 64;

  {
    const int n = t & 31;
    const int jb = (t >> 5) * 8;
    float v[8];
#pragma unroll
    for (int i = 0; i < 8; ++i) v[i] = bout[j0 + jb + i];
    if (NS == 4) {
      float pv[4][8];
#pragma unroll
      for (int s = 0; s < 4; ++s) {
        const float* P = logitsP + (size_t)s * (NV * 32) + (size_t)(j0 + jb) * 32 + n;
#pragma unroll
        for (int i = 0; i < 8; ++i) pv[s][i] = ldc(P + (size_t)i * 32);
      }
#pragma unroll
      for (int s = 0; s < 4; ++s)
#pragma unroll
        for (int i = 0; i < 8; ++i) v[i] += pv[s][i];
    } else {
      for (int s = 0; s < NS; ++s) {
        const float* P = logitsP + (size_t)s * (NV * 32) + (size_t)(j0 + jb) * 32 + n;
#pragma unroll
        for (int i = 0; i < 8; ++i) v[i] += ldc(P + (size_t)i * 32);
      }
    }
#pragma unroll
    for (int i = 0; i < 8; ++i) tile[jb + i][n] = v[i];
  }
  __syncthreads();
  {
    const int jl = t & 63;
    const int wq = t >> 6;
#pragma unroll
    for (int q = 0; q < 8; ++q) {
      const int nn = wq * 8 + q;
      float val = tile[jl][nn];
      stc(logitsN + (size_t)nn * NV + j0 + jl, val);
      float m = val;
      m = fmaxf(m, __shfl_xor(m, 1, 64));
      m = fmaxf(m, __shfl_xor(m, 2, 64));
      m = fmaxf(m, __shfl_xor(m, 4, 64));
      m = fmaxf(m, __shfl_xor(m, 8, 64));
      m = fmaxf(m, __shfl_xor(m, 16, 64));
      m = fmaxf(m, __shfl_xor(m, 32, 64));
      float sx = expf(val - m);
      sx += __shfl_xor(sx, 1, 64);
      sx += __shfl_xor(sx, 2, 64);
      sx += __shfl_xor(sx, 4, 64);
      sx += __shfl_xor(sx, 8, 64);
      sx += __shfl_xor(sx, 16, 64);
      sx += __shfl_xor(sx, 32, 64);
      if (jl == 0)
        stc2(lsePart + (size_t)bx * 64 + nn * 2, make_float2(m, sx));
    }
  }
}

struct TAsh { float pm[32][8]; float ps[32][8]; float A[8]; ull wm[4]; };

__device__ __forceinline__ void topkA_one(
    int b, int c, TAsh* S,
    const float* __restrict__ logitsN, const float* __restrict__ lsePart,
    const float* __restrict__ prev_vals, const int* __restrict__ prev_tok,
    int eos, ull* __restrict__ top8A, int mode)
{
  const int t = threadIdx.x;

  // phase 1: finish logsumexp over 500 partials. Batch-load all 16 partials
  // first (identity pad for p>=500: combining (-3e38,0) is a bit-exact no-op),
  // then combine in ascending-p order (same order as before).
  {
    const int n8 = t & 7;
    const int grp = t >> 3;
    float2 qq[16];
#pragma unroll
    for (int k2 = 0; k2 < 16; ++k2) {
      int p = grp + k2 * 32;
      qq[k2] = (p < 500) ? ldc2(lsePart + (size_t)p * 64 + (b * 8 + n8) * 2)
                         : make_float2(-3.0e38f, 0.f);
    }
    float m = -3.0e38f, s = 0.f;
#pragma unroll
    for (int k2 = 0; k2 < 16; ++k2) {
      float Mx = fmaxf(m, qq[k2].x);
      s = s * expf(m - Mx) + qq[k2].y * expf(qq[k2].x - Mx);
      m = Mx;
    }
    S->pm[grp][n8] = m; S->ps[grp][n8] = s;
    __syncthreads();
    for (int off2 = 16; off2 >= 1; off2 >>= 1) {
      if (grp < off2) {
        float m1 = S->pm[grp][n8], s1 = S->ps[grp][n8];
        float m2 = S->pm[grp + off2][n8], s2 = S->ps[grp + off2][n8];
        float Mx = fmaxf(m1, m2);
        S->pm[grp][n8] = Mx;
        S->ps[grp][n8] = s1 * expf(m1 - Mx) + s2 * expf(m2 - Mx);
      }
      __syncthreads();
    }
    if (t < 8) S->A[t] = S->pm[0][t] + logf(S->ps[0][t]);
    __syncthreads();
  }

  ull t8[8];
#pragma unroll
  for (int j = 0; j < 8; ++j) t8[j] = 0ULL;

  auto ins = [&](ull key) {
    if (key > t8[7]) {
      t8[7] = key;
#pragma unroll
      for (int q = 7; q >= 1; --q) {
        ull hi = umax64(t8[q - 1], t8[q]);
        ull lo = umin64(t8[q - 1], t8[q]);
        t8[q - 1] = hi; t8[q] = lo;
      }
    }
  };

  // 4-wide scan (2x ldc2). Per-thread candidate redistribution is safe: the
  // 8-round extraction below is exact over the chunk's candidate union.
  if (mode == 1) {
    const int kb = c >> 2;
    const int v0 = (c & 3) * 8000;
    const bool fin = (ldci(prev_tok + b * 8 + kb) == eos);
    const float add = ldc(prev_vals + b * 8 + kb) - S->A[kb];
    const float* row = logitsN + (size_t)(b * 8 + kb) * NV;
    for (int v = v0 + t * 4; v < v0 + 8000; v += 1024) {
      float x0, x1, x2, x3;
      if (fin) {
        x0 = (v + 0 == eos) ? 0.f : -1e30f;
        x1 = (v + 1 == eos) ? 0.f : -1e30f;
        x2 = (v + 2 == eos) ? 0.f : -1e30f;
        x3 = (v + 3 == eos) ? 0.f : -1e30f;
      } else {
        float2 a0 = ldc2(row + v);
        float2 a1 = ldc2(row + v + 2);
        x0 = a0.x + add; x1 = a0.y + add; x2 = a1.x + add; x3 = a1.y + add;
      }
      ins(packkey(x0, (unsigned)(kb * NV + v + 0)));
      ins(packkey(x1, (unsigned)(kb * NV + v + 1)));
      ins(packkey(x2, (unsigned)(kb * NV + v + 2)));
      ins(packkey(x3, (unsigned)(kb * NV + v + 3)));
    }
  } else {
    const int v0 = c * 1000;
    const float add = -S->A[0];
    const float* row = logitsN + (size_t)(b * 8) * NV;
    for (int v = v0 + t * 4; v < v0 + 1000; v += 1024) {
      float2 a0 = ldc2(row + v);
      float2 a1 = ldc2(row + v + 2);
      ins(packkey(a0.x + add, (unsigned)(v + 0)));
      ins(packkey(a0.y + add, (unsigned)(v + 1)));
      ins(packkey(a1.x + add, (unsigned)(v + 2)));
      ins(packkey(a1.y + add, (unsigned)(v + 3)));
    }
  }

  // 8-round exact extraction (keys unique)
  int pi = 0;
  for (int r = 0; r < 8; ++r) {
    ull cand = (pi < 8) ? t8[pi] : 0ULL;
#pragma unroll
    for (int off = 1; off < 64; off <<= 1) cand = umax64(cand, __shfl_xor(cand, off, 64));
    if ((t & 63) == 0) S->wm[t >> 6] = cand;
    __syncthreads();
    ull win = umax64(umax64(S->wm[0], S->wm[1]), umax64(S->wm[2], S->wm[3]));
    if (pi < 8 && t8[pi] == win) ++pi;
    if (t == 0) stcu(top8A + ((size_t)b * 32 + c) * 8 + r, win);
    __syncthreads();
  }
}

struct TBsh { ull wm[4]; float vals8[8]; int tok8[8]; int which8[8]; };

__device__ __forceinline__ void topkB_one(
    int b, TBsh* S, const ull* __restrict__ top8A,
    float* __restrict__ prev_vals, int* __restrict__ prev_tok,
    const float* __restrict__ lp_src, float* __restrict__ lp_dst,
    const int* __restrict__ tok_src, int* __restrict__ tok_dst,
    const float* __restrict__ h2T, float* __restrict__ hT,
    const float* __restrict__ emb, float* __restrict__ embX,
    int step, int mode)
{
  const int t = threadIdx.x;

  ull mykey = ldcu(top8A + (size_t)b * 256 + t);
  int done = 0;
  for (int r = 0; r < 8; ++r) {
    ull cand = done ? 0ULL : mykey;
#pragma unroll
    for (int off = 1; off < 64; off <<= 1) cand = umax64(cand, __shfl_xor(cand, off, 64));
    if ((t & 63) == 0) S->wm[t >> 6] = cand;
    __syncthreads();
    ull win = umax64(umax64(S->wm[0], S->wm[1]), umax64(S->wm[2], S->wm[3]));
    if (!done && mykey == win) done = 1;
    if (t == 0) {
      unsigned idx = 0xFFFFFFFFu - (unsigned)(win & 0xFFFFFFFFull);
      unsigned u = (unsigned)(win >> 32);
      u = (u >> 31) ? (u ^ 0x80000000u) : ~u;
      S->vals8[r] = __uint_as_float(u);
      if (mode == 1) { S->tok8[r] = (int)(idx % NV); S->which8[r] = (int)(idx / NV); }
      else { S->tok8[r] = (int)idx; S->which8[r] = r; }
    }
    __syncthreads();
  }

  if (t < 8) {
    stc(prev_vals + b * 8 + t, S->vals8[t]);
    stci(prev_tok + b * 8 + t, S->tok8[t]);
  }
  for (int idx = t; idx < 512; idx += 256) {
    int j = idx >> 6;
    int tt = idx & 63;
    float lv; int tv;
    if (tt == step) { lv = S->vals8[j]; tv = S->tok8[j]; }
    else if (mode == 0) { lv = 0.f; tv = 0; }
    else {
      int w = S->which8[j];
      lv = ldc(lp_src + b * 512 + w * 64 + tt);
      tv = ldci(tok_src + b * 512 + w * 64 + tt);
    }
    stc(lp_dst + b * 512 + idx, lv);
    stci(tok_dst + b * 512 + idx, tv);
  }
  for (int idx = t; idx < 8192; idx += 256) {
    int kk = idx >> 3;
    int j = idx & 7;
    stc(hT + kk * 32 + b * 8 + j, ldc(h2T + kk * 32 + b * 8 + S->which8[j]));
  }
  {
    int j = t >> 5;
    int kbase = (t & 31) * 16;
    const float* src = emb + (size_t)S->tok8[j] * EMB + kbase;
#pragma unroll
    for (int q = 0; q < 4; ++q) {
      float4 v = *(const float4*)(src + 4 * q);
      stc(embX + (kbase + 4 * q + 0) * 32 + b * 8 + j, v.x);
      stc(embX + (kbase + 4 * q + 1) * 32 + b * 8 + j, v.y);
      stc(embX + (kbase + 4 * q + 2) * 32 + b * 8 + j, v.z);
      stc(embX + (kbase + 4 * q + 3) * 32 + b * 8 + j, v.w);
    }
  }
}

// ---------------------------------------------------------------------------
// Mega-kernel: entire 64-step loop in one cooperative launch. W=512 (2/CU).
// ---------------------------------------------------------------------------
union MegaLDS {
  struct { float x[128 * 32]; float w[4][2][16 * WP]; } gp;  // 50 KiB
  float tile[64][33];
  TAsh ta;
  TBsh tb;
};

struct MegaArgs {
  const float* encoded; const float* embedding;
  const float* Wih; const float* Whh; const float* bih; const float* bhh;
  const float* Wout; const float* bout;
  const int* bosp; const int* eosp;
  float* hT; float* h2T; float* embX; float* gHp; float* gIp;
  float* logitsN; float* lsePart; ull* top8A;
  float* prev_vals; int* prev_tok;
  float* lp0; float* lp1; int* tok0; int* tok1;
  float* logitsP; int NS;
  GridBar* gb; float* outp;
};

__global__ __launch_bounds__(256, 2) void k_mega(MegaArgs a)
{
  __shared__ MegaLDS L;
  const int W = (int)gridDim.x;
  const int bid = (int)blockIdx.x;
  const int t = (int)threadIdx.x;
  const int KperS = 1024 / a.NS;
  const int NPANL = 125 * a.NS;
  unsigned bgen = 0;

  // prep: hT / embX for step 0
  for (int g = bid * 256 + t; g < 49152; g += W * 256) {
    if (g < 32768) {
      int k = g >> 5, n = g & 31;
      stc(a.hT + g, a.encoded[(n >> 3) * HID + k]);
    } else {
      int g2 = g - 32768;
      int k = g2 >> 5;
      stc(a.embX + g2, a.embedding[(size_t)(*a.bosp) * EMB + k]);
    }
  }
  gridbar(a.gb, W, ++bgen);
  const int eos = *a.eosp;

  for (int st = 0; st < NT; ++st) {
    // ---- gates (144 panels) ----
    for (int p = bid; p < 144; p += W) {
      if (p < 96) {
        int jt = p % 12, s = p / 12;
        gemm_panel_m<128>(L.gp.x, L.gp.w, a.Whh + (size_t)jt * 256 * HID, HID, s * 128, 1,
                          a.hT, a.gHp + (size_t)s * (3072 * 32) + (size_t)jt * 256 * 32);
      } else {
        int r = p - 96, jt = r % 12, s = r / 12;
        gemm_panel_m<128>(L.gp.x, L.gp.w, a.Wih + (size_t)jt * 256 * EMB, EMB, s * 128, 1,
                          a.embX, a.gIp + (size_t)s * (3072 * 32) + (size_t)jt * 256 * 32);
      }
    }
    gridbar(a.gb, W, ++bgen);

    // ---- combine -> h2T ----
    for (int g = bid * 256 + t; g < 32768; g += W * 256)
      combine_one(g, a.gHp, a.gIp, a.bih, a.bhh, a.hT, a.h2T);
    gridbar(a.gb, W, ++bgen);

    // ---- logits (125*NS panels) ----
    for (int p = bid; p < NPANL; p += W) {
      int jt = p % 125, s = p / 125;
      gemm_panel_m<128>(L.gp.x, L.gp.w, a.Wout + (size_t)jt * 256 * HID, HID, s * KperS,
                        KperS / 128, a.h2T,
                        a.logitsP + (size_t)s * (NV * 32) + (size_t)jt * 256 * 32);
    }
    gridbar(a.gb, W, ++bgen);

    // ---- reduce: sum slabs + bias, transpose, lse partials ----
    for (int c = bid; c < 500; c += W) {
      reduce_one(c, L.tile, a.logitsP, a.bout, a.logitsN, a.lsePart, a.NS);
      __syncthreads();
    }
    gridbar(a.gb, W, ++bgen);

    const int mode = (st == 0) ? 0 : 1;

    // ---- topkA (128 items) ----
    for (int it = bid; it < 128; it += W)
      topkA_one(it >> 5, it & 31, &L.ta, a.logitsN, a.lsePart, a.prev_vals, a.prev_tok,
                eos, a.top8A, mode);
    gridbar(a.gb, W, ++bgen);

    // ---- topkB (4 items) ----
    {
      float* lps = (st & 1) ? a.lp0 : a.lp1;
      float* lpd = (st & 1) ? a.lp1 : a.lp0;
      int* tks = (st & 1) ? a.tok0 : a.tok1;
      int* tkd = (st & 1) ? a.tok1 : a.tok0;
      for (int b = bid; b < NB; b += W)
        topkB_one(b, &L.tb, a.top8A, a.prev_vals, a.prev_tok, lps, lpd, tks, tkd,
                  a.h2T, a.hT, a.embedding, a.embX, st, mode);
    }
    gridbar(a.gb, W, ++bgen);
  }

  // final: out = [lp_hist, tok_hist as float]
  for (int g = bid * 256 + t; g < 4096; g += W * 256) {
    if (g < 2048) a.outp[g] = ldc(a.lp1 + g);
    else a.outp[g] = (float)ldci(a.tok1 + g - 2048);
  }
}

// ---------------------------------------------------------------------------
// Fallback kernels (original multi-launch path), sharing the same bodies.
// ---------------------------------------------------------------------------
__global__ void k_prep(const float* __restrict__ encoded, const float* __restrict__ emb,
                       const int* __restrict__ bosp,
                       float* __restrict__ hT, float* __restrict__ embX)
{
  int g = blockIdx.x * 256 + threadIdx.x;   // 49152
  if (g < 32768) {
    int k = g >> 5, n = g & 31;
    stc(hT + g, encoded[(n >> 3) * HID + k]);
  } else {
    int g2 = g - 32768;
    int k = g2 >> 5;
    stc(embX + g2, emb[(size_t)(*bosp) * EMB + k]);
  }
}

__global__ __launch_bounds__(256, 2) void k_gates(
    const float* __restrict__ Wih, const float* __restrict__ Whh,
    const float* __restrict__ embX, const float* __restrict__ hT,
    float* __restrict__ gHp, float* __restrict__ gIp)
{
  __shared__ float xlds[128 * 32];
  __shared__ float wlds[4][2][16 * WP];
  const int bx = blockIdx.x;
  if (bx < 96) {
    const int jt = bx % 12, s = bx / 12;
    gemm_panel_m<128>(xlds, wlds, Whh + (size_t)jt * 256 * HID, HID, s * 128, 1, hT,
                      gHp + (size_t)s * (3072 * 32) + (size_t)jt * 256 * 32);
  } else {
    const int r = bx - 96;
    const int jt = r % 12, s = r / 12;
    gemm_panel_m<128>(xlds, wlds, Wih + (size_t)jt * 256 * EMB, EMB, s * 128, 1, embX,
                      gIp + (size_t)s * (3072 * 32) + (size_t)jt * 256 * 32);
  }
}

__global__ __launch_bounds__(256) void k_combine(
    const float* __restrict__ gHp, const float* __restrict__ gIp,
    const float* __restrict__ bih, const float* __restrict__ bhh,
    const float* __restrict__ hT, float* __restrict__ h2T)
{
  int g = blockIdx.x * 256 + threadIdx.x;   // 32768
  combine_one(g, gHp, gIp, bih, bhh, hT, h2T);
}

__global__ __launch_bounds__(256, 2) void k_logits(
    const float* __restrict__ Wout, const float* __restrict__ h2T,
    float* __restrict__ logitsP, int NS)
{
  __shared__ float xlds[128 * 32];
  __shared__ float wlds[4][2][16 * WP];
  const int jt = blockIdx.x % 125;
  const int s = blockIdx.x / 125;
  const int KperS = 1024 / NS;
  gemm_panel_m<128>(xlds, wlds, Wout + (size_t)jt * 256 * HID, HID, s * KperS, KperS / 128,
                    h2T, logitsP + (size_t)s * (NV * 32) + (size_t)jt * 256 * 32);
}

__global__ __launch_bounds__(256) void k_reduce(
    const float* __restrict__ logitsP, const float* __restrict__ bout,
    float* __restrict__ logitsN, float* __restrict__ lsePart, int NS)
{
  __shared__ float tile[64][33];
  reduce_one(blockIdx.x, tile, logitsP, bout, logitsN, lsePart, NS);
}

__global__ __launch_bounds__(256) void k_topkA(
    const float* __restrict__ logitsN, const float* __restrict__ lsePart,
    const float* __restrict__ prev_vals, const int* __restrict__ prev_tok,
    const int* __restrict__ eosp, ull* __restrict__ top8A, int mode)
{
  __shared__ TAsh S;
  topkA_one(blockIdx.x >> 5, blockIdx.x & 31, &S, logitsN, lsePart, prev_vals, prev_tok,
            *eosp, top8A, mode);
}

__global__ __launch_bounds__(256) void k_topkB(
    const ull* __restrict__ top8A,
    float* __restrict__ prev_vals, int* __restrict__ prev_tok,
    const float* __restrict__ lp_src, float* __restrict__ lp_dst,
    const int* __restrict__ tok_src, int* __restrict__ tok_dst,
    const float* __restrict__ h2T, float* __restrict__ hT,
    const float* __restrict__ emb, float* __restrict__ embX,
    int step, int mode)
{
  __shared__ TBsh S;
  topkB_one(blockIdx.x, &S, top8A, prev_vals, prev_tok, lp_src, lp_dst, tok_src, tok_dst,
            h2T, hT, emb, embX, step, mode);
}

__global__ void k_final(const float* __restrict__ lp_hist, const int* __restrict__ tok_hist,
                        float* __restrict__ out)
{
  int g = blockIdx.x * 256 + threadIdx.x;   // 4096
  if (g < 2048) out[g] = ldc(lp_hist + g);
  else out[g] = (float)ldci(tok_hist + g - 2048);
}

extern "C" void kernel_launch(void* const* d_in, const int* in_sizes, int n_in,
                              void* d_out, int out_size, void* d_ws, size_t ws_size,
                              hipStream_t stream)
{
  (void)in_sizes; (void)n_in; (void)out_size;
  const float* encoded   = (const float*)d_in[0];
  const float* embedding = (const float*)d_in[1];
  const float* Wih       = (const float*)d_in[2];
  const float* Whh       = (const float*)d_in[3];
  const float* bih       = (const float*)d_in[4];
  const float* bhh       = (const float*)d_in[5];
  const float* Wout      = (const float*)d_in[6];
  const float* bout      = (const float*)d_in[7];
  const int*   bosp      = (const int*)d_in[8];
  const int*   eosp      = (const int*)d_in[9];

  char* p = (char*)d_ws;
  size_t off = 0;
  auto ALLOC = [&](size_t bytes) -> void* {
    void* r = p + off;
    off += (bytes + 255) & ~(size_t)255;
    return r;
  };
  float* hT        = (float*)ALLOC((size_t)HID * 32 * 4);
  float* h2T       = (float*)ALLOC((size_t)HID * 32 * 4);
  float* embX      = (float*)ALLOC((size_t)EMB * 32 * 4);
  float* gHp       = (float*)ALLOC((size_t)8 * 3072 * 32 * 4);   // 3.15 MB
  float* gIp       = (float*)ALLOC((size_t)4 * 3072 * 32 * 4);   // 1.57 MB
  // logitsN overlays gHp+gIp (consumed by combine before reduce writes it;
  // gates rewrites next step only after topkA has consumed logitsN).
  float* logitsN   = gHp;
  float* lsePart   = (float*)ALLOC((size_t)500 * 64 * 4);
  ull*   top8A     = (ull*)ALLOC((size_t)NB * 32 * 8 * 8);
  float* prev_vals = (float*)ALLOC(32 * 4);
  int*   prev_tok  = (int*)ALLOC(32 * 4);
  float* lp0       = (float*)ALLOC(2048 * 4);
  float* lp1       = (float*)ALLOC(2048 * 4);
  int*   tok0      = (int*)ALLOC(2048 * 4);
  int*   tok1      = (int*)ALLOC(2048 * 4);
  GridBar* gb      = (GridBar*)ALLOC(sizeof(GridBar));

  int NS = 4;
  if (off + (size_t)4 * NV * 32 * 4 > ws_size) NS = 2;
  if (off + (size_t)2 * NV * 32 * 4 > ws_size) NS = 1;
  float* logitsP = (float*)ALLOC((size_t)NS * NV * 32 * 4);

  // ---- preferred path: one cooperative launch for the whole loop ----
  k_zero<<<1, 512, 0, stream>>>((unsigned*)gb);

  MegaArgs ma;
  ma.encoded = encoded; ma.embedding = embedding;
  ma.Wih = Wih; ma.Whh = Whh; ma.bih = bih; ma.bhh = bhh;
  ma.Wout = Wout; ma.bout = bout; ma.bosp = bosp; ma.eosp = eosp;
  ma.hT = hT; ma.h2T = h2T; ma.embX = embX; ma.gHp = gHp; ma.gIp = gIp;
  ma.logitsN = logitsN; ma.lsePart = lsePart; ma.top8A = top8A;
  ma.prev_vals = prev_vals; ma.prev_tok = prev_tok;
  ma.lp0 = lp0; ma.lp1 = lp1; ma.tok0 = tok0; ma.tok1 = tok1;
  ma.logitsP = logitsP; ma.NS = NS; ma.gb = gb; ma.outp = (float*)d_out;

  int occ = 0;
  if (hipOccupancyMaxActiveBlocksPerMultiprocessor(&occ, k_mega, 256, 0) != hipSuccess ||
      occ < 1) occ = 1;
  const int W = (occ >= 2) ? 512 : 256;   // 2 WG/CU -> 2 waves/SIMD

  void* kargs[] = { &ma };
  hipError_t e = hipLaunchCooperativeKernel(k_mega, dim3(W), dim3(256), kargs, 0, stream);
  if (e == hipSuccess) return;
  (void)hipGetLastError();  // clear error state; fall back to multi-launch path

  // ---- fallback: original (proven) multi-launch sequence ----
  k_prep<<<192, 256, 0, stream>>>(encoded, embedding, bosp, hT, embX);
  for (int t = 0; t < NT; ++t) {
    k_gates<<<144, 256, 0, stream>>>(Wih, Whh, embX, hT, gHp, gIp);
    k_combine<<<128, 256, 0, stream>>>(gHp, gIp, bih, bhh, hT, h2T);
    k_logits<<<125 * NS, 256, 0, stream>>>(Wout, h2T, logitsP, NS);
    k_reduce<<<500, 256, 0, stream>>>(logitsP, bout, logitsN, lsePart, NS);
    const int mode = (t == 0) ? 0 : 1;
    k_topkA<<<128, 256, 0, stream>>>(logitsN, lsePart, prev_vals, prev_tok, eosp, top8A, mode);
    float* lps = (t & 1) ? lp0 : lp1;
    float* lpd = (t & 1) ? lp1 : lp0;
    int*   tks = (t & 1) ? tok0 : tok1;
    int*   tkd = (t & 1) ? tok1 : tok0;
    k_topkB<<<NB, 256, 0, stream>>>(top8A, prev_vals, prev_tok, lps, lpd, tks, tkd,
                                    h2T, hT, embedding, embX, t, mode);
  }
  k_final<<<16, 256, 0, stream>>>(lp1, tok1, (float*)d_out);
}